// Round 1
// baseline (287.655 us; speedup 1.0000x reference)
//
#include <hip/hip_runtime.h>
#include <math.h>

#define NN 65536
#define NG 64
#define NPG 1024
#define HID 128
#define KNN 16
#define BINF 1e30f

typedef unsigned long long ull;

// ---------------------------------------------------------------- build Z
// Z[i][0:16] = x[i][1:17]; Z[i][16+j] = t_i * te_w[j] + te_b[j]
__global__ void k_build_z(const float* __restrict__ x,
                          const float* __restrict__ te_w,
                          const float* __restrict__ te_b,
                          float* __restrict__ Z) {
    int i = blockIdx.x * blockDim.x + threadIdx.x;
    if (i >= NN) return;
    const float* xr = x + (size_t)i * 17;
    float t = xr[0];
    float* zr = Z + (size_t)i * 48;
#pragma unroll
    for (int k = 0; k < 16; k++) zr[k] = xr[1 + k];
#pragma unroll
    for (int j = 0; j < 32; j++) zr[16 + j] = fmaf(t, te_w[j], te_b[j]);
}

// ---------------------------------------------------------------- input GLU
// H[i][c] = (Z@wl + bl) * sigmoid(Z@wg + bg), K=48
__global__ __launch_bounds__(256) void k_glu(const float* __restrict__ Z,
                                             const float* __restrict__ wl,
                                             const float* __restrict__ bl,
                                             const float* __restrict__ wg,
                                             const float* __restrict__ bg,
                                             float* __restrict__ H) {
    __shared__ float Xs[48][65];                 // padded: broadcast scalar reads
    __shared__ __align__(16) float Wl[48][128];
    __shared__ __align__(16) float Wg[48][128];
    int tid = threadIdx.x;
    int m0 = blockIdx.x * 64;

    // X tile: 64 nodes x 48 k  (768 float4)
#pragma unroll
    for (int p = 0; p < 3; p++) {
        int idx = tid + p * 256;         // 0..767
        int m = idx / 12, kq = idx % 12;
        float4 v = *(const float4*)(Z + (size_t)(m0 + m) * 48 + kq * 4);
        Xs[kq * 4 + 0][m] = v.x; Xs[kq * 4 + 1][m] = v.y;
        Xs[kq * 4 + 2][m] = v.z; Xs[kq * 4 + 3][m] = v.w;
    }
    // W tiles: 48x128 each (1536 float4 each)
#pragma unroll
    for (int p = 0; p < 6; p++) {
        int idx = tid + p * 256;         // 0..1535
        int k = idx / 32, c4 = idx % 32;
        *(float4*)&Wl[k][c4 * 4] = *(const float4*)(wl + k * 128 + c4 * 4);
        *(float4*)&Wg[k][c4 * 4] = *(const float4*)(wg + k * 128 + c4 * 4);
    }
    __syncthreads();

    int tr = tid >> 5, tc = tid & 31;    // 8 node-groups x 32 ch-groups
    float accL[8][4] = {}, accG[8][4] = {};
    for (int k = 0; k < 48; k++) {
        float xv[8];
#pragma unroll
        for (int i = 0; i < 8; i++) xv[i] = Xs[k][tr * 8 + i];
        float4 a = *(float4*)&Wl[k][tc * 4];
        float4 b = *(float4*)&Wg[k][tc * 4];
        float wa[4] = {a.x, a.y, a.z, a.w};
        float wb[4] = {b.x, b.y, b.z, b.w};
#pragma unroll
        for (int i = 0; i < 8; i++)
#pragma unroll
            for (int j = 0; j < 4; j++) {
                accL[i][j] = fmaf(xv[i], wa[j], accL[i][j]);
                accG[i][j] = fmaf(xv[i], wb[j], accG[i][j]);
            }
    }
    float4 vbl = *(const float4*)(bl + tc * 4);
    float4 vbg = *(const float4*)(bg + tc * 4);
    float bL[4] = {vbl.x, vbl.y, vbl.z, vbl.w};
    float bG[4] = {vbg.x, vbg.y, vbg.z, vbg.w};
#pragma unroll
    for (int i = 0; i < 8; i++) {
        int node = m0 + tr * 8 + i;
        float4 o;
        float tmp[4];
#pragma unroll
        for (int j = 0; j < 4; j++) {
            float lin = accL[i][j] + bL[j];
            float gat = accG[i][j] + bG[j];
            tmp[j] = lin / (1.0f + expf(-gat));
        }
        o.x = tmp[0]; o.y = tmp[1]; o.z = tmp[2]; o.w = tmp[3];
        *(float4*)(H + (size_t)node * 128 + tc * 4) = o;
    }
}

// ---------------------------------------------------------------- temporal kNN
// Per graph: bitonic-sort (t, idx) keys, then 16-step two-pointer merge.
__global__ __launch_bounds__(1024) void k_topk(const float* __restrict__ x,
                                               int* __restrict__ nbr) {
    __shared__ ull key[1024];
    __shared__ float st[1024];
    __shared__ int sidx[1024];
    __shared__ int rnk[1024];
    int i = threadIdx.x;
    int g = blockIdx.x;
    float t = x[(size_t)(g * NPG + i) * 17];
    unsigned ub = __float_as_uint(t);
    ub = (ub & 0x80000000u) ? ~ub : (ub | 0x80000000u);   // order-preserving map
    key[i] = ((ull)ub << 32) | (unsigned)i;

    for (int k = 2; k <= 1024; k <<= 1) {
        for (int j = k >> 1; j > 0; j >>= 1) {
            __syncthreads();
            int ixj = i ^ j;
            if (ixj > i) {
                ull a = key[i], b = key[ixj];
                bool up = ((i & k) == 0);
                if ((a > b) == up) { key[i] = b; key[ixj] = a; }
            }
        }
    }
    __syncthreads();
    ull kk = key[i];
    int oi = (int)(kk & 0xffffffffu);
    st[i] = x[(size_t)(g * NPG + oi) * 17];
    sidx[i] = oi;
    rnk[oi] = i;
    __syncthreads();

    int r = rnk[i];
    int L = r - 1, R = r + 1;
    int* out = nbr + (size_t)(g * NPG + i) * KNN;
#pragma unroll
    for (int q = 0; q < KNN; q++) {
        float dl = (L >= 0)   ? (t - st[L]) : BINF;
        float dr = (R < 1024) ? (st[R] - t) : BINF;
        bool left;
        if (dl < dr) left = true;
        else if (dr < dl) left = false;
        else left = (sidx[L] < sidx[R]);   // tie: lower original index (lax.top_k)
        int j;
        if (left) { j = sidx[L]; L--; }
        else      { j = sidx[R]; R++; }
        out[q] = g * NPG + j;              // global row index
    }
}

// ---------------------------------------------------------------- dual GEMM
// A = X @ (W_top - W_bot) + bias ; B = X @ W_bot.  cw is (256,128).
__global__ __launch_bounds__(256) void k_dual(const float* __restrict__ X,
                                              const float* __restrict__ cw,
                                              const float* __restrict__ cb,
                                              float* __restrict__ A,
                                              float* __restrict__ B) {
    __shared__ float Xs[32][65];
    __shared__ __align__(16) float W1[32][128];
    __shared__ __align__(16) float W2[32][128];
    int tid = threadIdx.x;
    int m0 = blockIdx.x * 64;
    int tr = tid >> 5, tc = tid & 31;
    float accA[8][4] = {}, accB[8][4] = {};

    for (int kb = 0; kb < 4; kb++) {
        __syncthreads();
        // X chunk: 64 x 32 (512 float4)
#pragma unroll
        for (int p = 0; p < 2; p++) {
            int idx = tid + p * 256;     // 0..511
            int m = idx / 8, kq = idx % 8;
            float4 v = *(const float4*)(X + (size_t)(m0 + m) * 128 + kb * 32 + kq * 4);
            Xs[kq * 4 + 0][m] = v.x; Xs[kq * 4 + 1][m] = v.y;
            Xs[kq * 4 + 2][m] = v.z; Xs[kq * 4 + 3][m] = v.w;
        }
        // W chunk: 32 x 128, top & bottom
#pragma unroll
        for (int p = 0; p < 4; p++) {
            int idx = tid + p * 256;     // 0..1023
            int k = idx / 32, c4 = idx % 32;
            float4 tp = *(const float4*)(cw + (size_t)(kb * 32 + k) * 128 + c4 * 4);
            float4 bt = *(const float4*)(cw + (size_t)(128 + kb * 32 + k) * 128 + c4 * 4);
            float4 d;
            d.x = tp.x - bt.x; d.y = tp.y - bt.y; d.z = tp.z - bt.z; d.w = tp.w - bt.w;
            *(float4*)&W1[k][c4 * 4] = d;
            *(float4*)&W2[k][c4 * 4] = bt;
        }
        __syncthreads();
        for (int k = 0; k < 32; k++) {
            float xv[8];
#pragma unroll
            for (int i = 0; i < 8; i++) xv[i] = Xs[k][tr * 8 + i];
            float4 a = *(float4*)&W1[k][tc * 4];
            float4 b = *(float4*)&W2[k][tc * 4];
            float wa[4] = {a.x, a.y, a.z, a.w};
            float wb[4] = {b.x, b.y, b.z, b.w};
#pragma unroll
            for (int i = 0; i < 8; i++)
#pragma unroll
                for (int j = 0; j < 4; j++) {
                    accA[i][j] = fmaf(xv[i], wa[j], accA[i][j]);
                    accB[i][j] = fmaf(xv[i], wb[j], accB[i][j]);
                }
        }
    }
    float4 vb = *(const float4*)(cb + tc * 4);
    float bb[4] = {vb.x, vb.y, vb.z, vb.w};
#pragma unroll
    for (int i = 0; i < 8; i++) {
        int node = m0 + tr * 8 + i;
        float4 oa, ob;
        oa.x = accA[i][0] + bb[0]; oa.y = accA[i][1] + bb[1];
        oa.z = accA[i][2] + bb[2]; oa.w = accA[i][3] + bb[3];
        ob.x = accB[i][0]; ob.y = accB[i][1]; ob.z = accB[i][2]; ob.w = accB[i][3];
        *(float4*)(A + (size_t)node * 128 + tc * 4) = oa;
        *(float4*)(B + (size_t)node * 128 + tc * 4) = ob;
    }
}

// ---------------------------------------------------------------- gather-max
// out[i][c] = relu(A[i][c] + max_{j} B[nbr[i][j]][c]); out==A in-place is safe.
__global__ __launch_bounds__(256) void k_gather(const float* __restrict__ A,
                                                const float* __restrict__ B,
                                                const int* __restrict__ nbr,
                                                float* __restrict__ out) {
    int gid = blockIdx.x * 256 + threadIdx.x;
    int i = gid >> 7, c = gid & 127;
    const int* nb = nbr + (size_t)i * KNN;
    float m = -BINF;
#pragma unroll
    for (int j = 0; j < KNN; j++) {
        int r = nb[j];
        m = fmaxf(m, B[(size_t)r * 128 + c]);
    }
    out[gid] = fmaxf(A[gid] + m, 0.0f);
}

// ---------------------------------------------------------------- pooling partials
// blockIdx = g*16 + chunk ; thread c in 0..255 covers comb channel c
__global__ __launch_bounds__(256) void k_pool(const float* __restrict__ x1,
                                              const float* __restrict__ x2,
                                              float* __restrict__ partM,
                                              float* __restrict__ partS) {
    int bx = blockIdx.x;
    int g = bx >> 4, ch = bx & 15;
    int c = threadIdx.x;
    const float* src = (c < 128) ? x1 : x2;
    int cc = c & 127;
    int base = g * NPG + ch * 64;
    float mx = -BINF, sm = 0.0f;
    for (int nd = 0; nd < 64; nd++) {
        float v = src[(size_t)(base + nd) * 128 + cc];
        mx = fmaxf(mx, v);
        sm += v;
    }
    partM[(size_t)bx * 256 + c] = mx;
    partS[(size_t)bx * 256 + c] = sm;
}

// ---------------------------------------------------------------- final head
__global__ __launch_bounds__(256) void k_final(const float* __restrict__ partM,
                                               const float* __restrict__ partS,
                                               const float* __restrict__ fg_lw,
                                               const float* __restrict__ fg_lb,
                                               const float* __restrict__ fg_gw,
                                               const float* __restrict__ fg_gb,
                                               const float* __restrict__ out_w,
                                               const float* __restrict__ out_b,
                                               float* __restrict__ out) {
    __shared__ float pooled[512];
    __shared__ float linv[128], gatev[128];
    __shared__ float gluv[128];
    __shared__ float lg[2];
    int g = blockIdx.x, tid = threadIdx.x;

    float mx = -BINF, sm = 0.0f;
    for (int ch = 0; ch < 16; ch++) {
        mx = fmaxf(mx, partM[(size_t)(g * 16 + ch) * 256 + tid]);
        sm += partS[(size_t)(g * 16 + ch) * 256 + tid];
    }
    pooled[tid] = mx;
    pooled[256 + tid] = sm * (1.0f / 1024.0f);
    __syncthreads();

    float acc = 0.0f;
    if (tid < 128) {
        for (int k = 0; k < 512; k++) acc = fmaf(pooled[k], fg_lw[k * 128 + tid], acc);
        linv[tid] = acc + fg_lb[tid];
    } else {
        int c = tid - 128;
        for (int k = 0; k < 512; k++) acc = fmaf(pooled[k], fg_gw[k * 128 + c], acc);
        gatev[c] = acc + fg_gb[c];
    }
    __syncthreads();
    if (tid < 128) gluv[tid] = linv[tid] / (1.0f + expf(-gatev[tid]));
    __syncthreads();
    if (tid < 2) {
        float s = out_b[tid];
        for (int c = 0; c < 128; c++) s = fmaf(gluv[c], out_w[c * 2 + tid], s);
        lg[tid] = s;
    }
    __syncthreads();
    if (tid < 2) {
        float m = fmaxf(lg[0], lg[1]);
        float lse = m + logf(expf(lg[0] - m) + expf(lg[1] - m));
        out[g * 2 + tid] = lg[tid] - lse;
    }
}

// ---------------------------------------------------------------- launch
extern "C" void kernel_launch(void* const* d_in, const int* in_sizes, int n_in,
                              void* d_out, int out_size, void* d_ws, size_t ws_size,
                              hipStream_t stream) {
    const float* x     = (const float*)d_in[0];
    const float* te_w  = (const float*)d_in[1];
    const float* te_b  = (const float*)d_in[2];
    const float* ig_lw = (const float*)d_in[3];
    const float* ig_lb = (const float*)d_in[4];
    const float* ig_gw = (const float*)d_in[5];
    const float* ig_gb = (const float*)d_in[6];
    const float* c1_w  = (const float*)d_in[7];
    const float* c1_b  = (const float*)d_in[8];
    const float* c2_w  = (const float*)d_in[9];
    const float* c2_b  = (const float*)d_in[10];
    const float* fg_lw = (const float*)d_in[11];
    const float* fg_lb = (const float*)d_in[12];
    const float* fg_gw = (const float*)d_in[13];
    const float* fg_gb = (const float*)d_in[14];
    const float* out_w = (const float*)d_in[15];
    const float* out_b = (const float*)d_in[16];
    float* out = (float*)d_out;

    // workspace layout (floats)
    float* base = (float*)d_ws;
    const size_t TENS = (size_t)NN * HID;       // 8.39M floats
    float* buf0 = base;                         // h, later A2/x2
    float* buf1 = base + TENS;                  // A1/x1
    float* buf2 = base + 2 * TENS;              // Z, later B1/B2
    int*   nbr  = (int*)(base + 3 * TENS);      // NN*16 ints
    float* partM = base + 3 * TENS + (size_t)NN * KNN;   // 1024*256
    float* partS = partM + 1024 * 256;

    k_build_z<<<NN / 256, 256, 0, stream>>>(x, te_w, te_b, buf2);
    k_glu<<<NN / 64, 256, 0, stream>>>(buf2, ig_lw, ig_lb, ig_gw, ig_gb, buf0);
    k_topk<<<NG, 1024, 0, stream>>>(x, nbr);
    // conv1: A1->buf1, B1->buf2 ; x1 = in-place buf1
    k_dual<<<NN / 64, 256, 0, stream>>>(buf0, c1_w, c1_b, buf1, buf2);
    k_gather<<<(NN * HID) / 256, 256, 0, stream>>>(buf1, buf2, nbr, buf1);
    // conv2: A2->buf0, B2->buf2 ; x2 = in-place buf0
    k_dual<<<NN / 64, 256, 0, stream>>>(buf1, c2_w, c2_b, buf0, buf2);
    k_gather<<<(NN * HID) / 256, 256, 0, stream>>>(buf0, buf2, nbr, buf0);

    k_pool<<<NG * 16, 256, 0, stream>>>(buf1, buf0, partM, partS);
    k_final<<<NG, 256, 0, stream>>>(partM, partS, fg_lw, fg_lb, fg_gw, fg_gb,
                                    out_w, out_b, out);
}

// Round 3
// 207.729 us; speedup vs baseline: 1.3848x; 1.3848x over previous
//
#include <hip/hip_runtime.h>
#include <math.h>

#define NN 65536
#define NG 64
#define NPG 1024
#define HID 128
#define KNN 16
#define BINF 1e30f

typedef unsigned long long ull;
typedef _Float16 f16;
typedef _Float16 f16x8 __attribute__((ext_vector_type(8)));
typedef float f32x4 __attribute__((ext_vector_type(4)));

// ---------------------------------------------------------------- weight prep
// Build fragment-ordered fp16 weight buffers for mfma_f32_16x16x32_f16.
// frag[mat][kt][nt][lane][i] = M[kt*32 + (lane>>4)*8 + i][nt*16 + (lane&15)]
// gfrag: GLU weights (K=48 padded to 64, KT=2), mats {ig_lw, ig_gw}  -> 16384 f16
// f1/f2: conv weights (K=128, KT=4), mats {W_top-W_bot, W_bot}      -> 32768 f16 each
__global__ __launch_bounds__(256) void k_prep(
    const float* __restrict__ ig_lw, const float* __restrict__ ig_gw,
    const float* __restrict__ c1_w, const float* __restrict__ c2_w,
    f16* __restrict__ gfrag, f16* __restrict__ f1, f16* __restrict__ f2) {
    int gid = blockIdx.x * 256 + threadIdx.x;   // [0, 81920)
    if (gid < 16384) {
        int i = gid & 7, lane = (gid >> 3) & 63, nt = (gid >> 9) & 7;
        int kt = (gid >> 12) & 1, mat = gid >> 13;
        int k = kt * 32 + ((lane >> 4) << 3) + i;
        int c = nt * 16 + (lane & 15);
        float v = 0.0f;
        if (k < 48) v = (mat ? ig_gw : ig_lw)[k * 128 + c];
        gfrag[gid] = (f16)v;
    } else {
        int g2 = gid - 16384;
        int buf = g2 >> 15;
        int rem = g2 & 32767;
        int mat = rem >> 14;
        int r2 = rem & 16383;
        int i = r2 & 7, lane = (r2 >> 3) & 63, nt = (r2 >> 9) & 7, kt = (r2 >> 12) & 3;
        int k = kt * 32 + ((lane >> 4) << 3) + i;
        int c = nt * 16 + (lane & 15);
        const float* cw = buf ? c2_w : c1_w;
        float top = cw[k * 128 + c];
        float bot = cw[(128 + k) * 128 + c];
        float v = mat ? bot : (top - bot);
        (buf ? f2 : f1)[rem] = (f16)v;
    }
}

// ---------------------------------------------------------------- MFMA GLU
// H = (Z@wl + bl) * sigmoid(Z@wg + bg); Z synthesized in-register:
// Z[i][0:16]=x[i][1:17], Z[i][16+j]=t_i*te_w[j]+te_b[j], Z[i][48:64]=0
__global__ __launch_bounds__(256) void k_glum(
    const float* __restrict__ x, const float* __restrict__ te_w,
    const float* __restrict__ te_b, const f16x8* __restrict__ wfrag,
    const float* __restrict__ bl, const float* __restrict__ bg,
    float* __restrict__ H) {
    __shared__ f16x8 XL[4 * 2 * 64];          // [mf][kt][lane]
    int tid = threadIdx.x;
    int r0 = blockIdx.x * 64;
#pragma unroll
    for (int p = 0; p < 2; p++) {
        int idx = tid + p * 256;              // [0,512)
        int row = idx >> 3, kq = idx & 7;
        int node = r0 + row;
        f16x8 h;
        if (kq < 2) {
            const float* xr = x + (size_t)node * 17 + 1 + kq * 8;
#pragma unroll
            for (int i = 0; i < 8; i++) h[i] = (f16)xr[i];
        } else if (kq < 6) {
            float t = x[(size_t)node * 17];
            int j0 = (kq - 2) * 8;
#pragma unroll
            for (int i = 0; i < 8; i++) h[i] = (f16)fmaf(t, te_w[j0 + i], te_b[j0 + i]);
        } else {
#pragma unroll
            for (int i = 0; i < 8; i++) h[i] = (f16)0.0f;
        }
        int mf = row >> 4, kt = kq >> 2, lane = ((kq & 3) << 4) | (row & 15);
        XL[(mf * 2 + kt) * 64 + lane] = h;
    }
    __syncthreads();
    int w = tid >> 6, lane = tid & 63;
    f32x4 acc[2][2][4];                        // [out][ntj][mf]
#pragma unroll
    for (int o = 0; o < 2; o++)
#pragma unroll
        for (int j = 0; j < 2; j++)
#pragma unroll
            for (int mf = 0; mf < 4; mf++) acc[o][j][mf] = (f32x4){0.f, 0.f, 0.f, 0.f};
#pragma unroll 1
    for (int kt = 0; kt < 2; kt++) {
        f16x8 wf0[2], wf1[2], xa[4];
#pragma unroll
        for (int j = 0; j < 2; j++) {
            wf0[j] = wfrag[((0 * 2 + kt) * 8 + (w * 2 + j)) * 64 + lane];
            wf1[j] = wfrag[((1 * 2 + kt) * 8 + (w * 2 + j)) * 64 + lane];
        }
#pragma unroll
        for (int mf = 0; mf < 4; mf++) xa[mf] = XL[(mf * 2 + kt) * 64 + lane];
#pragma unroll
        for (int mf = 0; mf < 4; mf++)
#pragma unroll
            for (int j = 0; j < 2; j++) {
                acc[0][j][mf] = __builtin_amdgcn_mfma_f32_16x16x32_f16(xa[mf], wf0[j], acc[0][j][mf], 0, 0, 0);
                acc[1][j][mf] = __builtin_amdgcn_mfma_f32_16x16x32_f16(xa[mf], wf1[j], acc[1][j][mf], 0, 0, 0);
            }
    }
#pragma unroll
    for (int j = 0; j < 2; j++) {
        int col = w * 32 + j * 16 + (lane & 15);
        float bbl = bl[col], bbg = bg[col];
#pragma unroll
        for (int mf = 0; mf < 4; mf++) {
            int rbase = r0 + mf * 16 + ((lane >> 4) << 2);
#pragma unroll
            for (int q = 0; q < 4; q++) {
                float lin = acc[0][j][mf][q] + bbl;
                float gat = acc[1][j][mf][q] + bbg;
                H[(size_t)(rbase + q) * 128 + col] = lin / (1.0f + expf(-gat));
            }
        }
    }
}

// ---------------------------------------------------------------- MFMA dual GEMM
// A = X @ W1 + bias ; B = X @ W2 (W already fragment-packed fp16)
__global__ __launch_bounds__(256) void k_dualm(
    const float* __restrict__ X, const f16x8* __restrict__ wfrag,
    const float* __restrict__ cb, float* __restrict__ A, float* __restrict__ B) {
    __shared__ f16x8 XL[4 * 4 * 64];          // [mf][kt][lane]
    int tid = threadIdx.x;
    int r0 = blockIdx.x * 64;
    // stage 64 rows x 128 k: 1024 octets, 4 passes of 256
#pragma unroll
    for (int p = 0; p < 4; p++) {
        int idx = tid + p * 256;              // [0,1024)
        int row = idx >> 4, kq = idx & 15;
        const float4* src = (const float4*)(X + (size_t)(r0 + row) * 128 + kq * 8);
        float4 v0 = src[0], v1 = src[1];
        f16x8 h;
        h[0] = (f16)v0.x; h[1] = (f16)v0.y; h[2] = (f16)v0.z; h[3] = (f16)v0.w;
        h[4] = (f16)v1.x; h[5] = (f16)v1.y; h[6] = (f16)v1.z; h[7] = (f16)v1.w;
        int mf = row >> 4, kt = kq >> 2, lane = ((kq & 3) << 4) | (row & 15);
        XL[(mf * 4 + kt) * 64 + lane] = h;
    }
    __syncthreads();
    int w = tid >> 6, lane = tid & 63;
    f32x4 acc[2][2][4];                        // [out][ntj][mf]
#pragma unroll
    for (int o = 0; o < 2; o++)
#pragma unroll
        for (int j = 0; j < 2; j++)
#pragma unroll
            for (int mf = 0; mf < 4; mf++) acc[o][j][mf] = (f32x4){0.f, 0.f, 0.f, 0.f};
#pragma unroll 1
    for (int kt = 0; kt < 4; kt++) {
        f16x8 wf0[2], wf1[2], xa[4];
#pragma unroll
        for (int j = 0; j < 2; j++) {
            wf0[j] = wfrag[((0 * 4 + kt) * 8 + (w * 2 + j)) * 64 + lane];
            wf1[j] = wfrag[((1 * 4 + kt) * 8 + (w * 2 + j)) * 64 + lane];
        }
#pragma unroll
        for (int mf = 0; mf < 4; mf++) xa[mf] = XL[(mf * 4 + kt) * 64 + lane];
#pragma unroll
        for (int mf = 0; mf < 4; mf++)
#pragma unroll
            for (int j = 0; j < 2; j++) {
                acc[0][j][mf] = __builtin_amdgcn_mfma_f32_16x16x32_f16(xa[mf], wf0[j], acc[0][j][mf], 0, 0, 0);
                acc[1][j][mf] = __builtin_amdgcn_mfma_f32_16x16x32_f16(xa[mf], wf1[j], acc[1][j][mf], 0, 0, 0);
            }
    }
#pragma unroll
    for (int j = 0; j < 2; j++) {
        int col = w * 32 + j * 16 + (lane & 15);
        float bias = cb[col];
#pragma unroll
        for (int mf = 0; mf < 4; mf++) {
            int rbase = r0 + mf * 16 + ((lane >> 4) << 2);
#pragma unroll
            for (int q = 0; q < 4; q++) {
                A[(size_t)(rbase + q) * 128 + col] = acc[0][j][mf][q] + bias;
                B[(size_t)(rbase + q) * 128 + col] = acc[1][j][mf][q];
            }
        }
    }
}

// ---------------------------------------------------------------- temporal kNN
__global__ __launch_bounds__(1024) void k_topk(const float* __restrict__ x,
                                               int* __restrict__ nbr) {
    __shared__ ull key[1024];
    __shared__ float st[1024];
    __shared__ int sidx[1024];
    __shared__ int rnk[1024];
    int i = threadIdx.x;
    int g = blockIdx.x;
    float t = x[(size_t)(g * NPG + i) * 17];
    unsigned ub = __float_as_uint(t);
    ub = (ub & 0x80000000u) ? ~ub : (ub | 0x80000000u);   // order-preserving map
    key[i] = ((ull)ub << 32) | (unsigned)i;

    for (int k = 2; k <= 1024; k <<= 1) {
        for (int j = k >> 1; j > 0; j >>= 1) {
            __syncthreads();
            int ixj = i ^ j;
            if (ixj > i) {
                ull a = key[i], b = key[ixj];
                bool up = ((i & k) == 0);
                if ((a > b) == up) { key[i] = b; key[ixj] = a; }
            }
        }
    }
    __syncthreads();
    ull kk = key[i];
    int oi = (int)(kk & 0xffffffffu);
    st[i] = x[(size_t)(g * NPG + oi) * 17];
    sidx[i] = oi;
    rnk[oi] = i;
    __syncthreads();

    int r = rnk[i];
    int L = r - 1, R = r + 1;
    int* out = nbr + (size_t)(g * NPG + i) * KNN;
#pragma unroll
    for (int q = 0; q < KNN; q++) {
        float dl = (L >= 0)   ? (t - st[L]) : BINF;
        float dr = (R < 1024) ? (st[R] - t) : BINF;
        bool left;
        if (dl < dr) left = true;
        else if (dr < dl) left = false;
        else left = (sidx[L] < sidx[R]);   // tie: lower original index (lax.top_k)
        int j;
        if (left) { j = sidx[L]; L--; }
        else      { j = sidx[R]; R++; }
        out[q] = g * NPG + j;              // global row index
    }
}

// ---------------------------------------------------------------- gather-max
__global__ __launch_bounds__(256) void k_gather(const float* __restrict__ A,
                                                const float* __restrict__ B,
                                                const int* __restrict__ nbr,
                                                float* __restrict__ out) {
    int gid = blockIdx.x * 256 + threadIdx.x;
    int i = gid >> 7, c = gid & 127;
    const int* nb = nbr + (size_t)i * KNN;
    float m = -BINF;
#pragma unroll
    for (int j = 0; j < KNN; j++) {
        int r = nb[j];
        m = fmaxf(m, B[(size_t)r * 128 + c]);
    }
    out[gid] = fmaxf(A[gid] + m, 0.0f);
}

// ---------------------------------------------------------------- pooling partials
__global__ __launch_bounds__(256) void k_pool(const float* __restrict__ x1,
                                              const float* __restrict__ x2,
                                              float* __restrict__ partM,
                                              float* __restrict__ partS) {
    int bx = blockIdx.x;
    int g = bx >> 4, ch = bx & 15;
    int c = threadIdx.x;
    const float* src = (c < 128) ? x1 : x2;
    int cc = c & 127;
    int base = g * NPG + ch * 64;
    float mx = -BINF, sm = 0.0f;
    for (int nd = 0; nd < 64; nd++) {
        float v = src[(size_t)(base + nd) * 128 + cc];
        mx = fmaxf(mx, v);
        sm += v;
    }
    partM[(size_t)bx * 256 + c] = mx;
    partS[(size_t)bx * 256 + c] = sm;
}

// ---------------------------------------------------------------- final head
__global__ __launch_bounds__(256) void k_final(const float* __restrict__ partM,
                                               const float* __restrict__ partS,
                                               const float* __restrict__ fg_lw,
                                               const float* __restrict__ fg_lb,
                                               const float* __restrict__ fg_gw,
                                               const float* __restrict__ fg_gb,
                                               const float* __restrict__ out_w,
                                               const float* __restrict__ out_b,
                                               float* __restrict__ out) {
    __shared__ float pooled[512];
    __shared__ float linv[128], gatev[128];
    __shared__ float gluv[128];
    __shared__ float lg[2];
    int g = blockIdx.x, tid = threadIdx.x;

    float mx = -BINF, sm = 0.0f;
    for (int ch = 0; ch < 16; ch++) {
        mx = fmaxf(mx, partM[(size_t)(g * 16 + ch) * 256 + tid]);
        sm += partS[(size_t)(g * 16 + ch) * 256 + tid];
    }
    pooled[tid] = mx;
    pooled[256 + tid] = sm * (1.0f / 1024.0f);
    __syncthreads();

    float acc = 0.0f;
    if (tid < 128) {
        for (int k = 0; k < 512; k++) acc = fmaf(pooled[k], fg_lw[k * 128 + tid], acc);
        linv[tid] = acc + fg_lb[tid];
    } else {
        int c = tid - 128;
        for (int k = 0; k < 512; k++) acc = fmaf(pooled[k], fg_gw[k * 128 + c], acc);
        gatev[c] = acc + fg_gb[c];
    }
    __syncthreads();
    if (tid < 128) gluv[tid] = linv[tid] / (1.0f + expf(-gatev[tid]));
    __syncthreads();
    if (tid < 2) {
        float s = out_b[tid];
        for (int c = 0; c < 128; c++) s = fmaf(gluv[c], out_w[c * 2 + tid], s);
        lg[tid] = s;
    }
    __syncthreads();
    if (tid < 2) {
        float m = fmaxf(lg[0], lg[1]);
        float lse = m + logf(expf(lg[0] - m) + expf(lg[1] - m));
        out[g * 2 + tid] = lg[tid] - lse;
    }
}

// ---------------------------------------------------------------- launch
extern "C" void kernel_launch(void* const* d_in, const int* in_sizes, int n_in,
                              void* d_out, int out_size, void* d_ws, size_t ws_size,
                              hipStream_t stream) {
    const float* x     = (const float*)d_in[0];
    const float* te_w  = (const float*)d_in[1];
    const float* te_b  = (const float*)d_in[2];
    const float* ig_lw = (const float*)d_in[3];
    const float* ig_lb = (const float*)d_in[4];
    const float* ig_gw = (const float*)d_in[5];
    const float* ig_gb = (const float*)d_in[6];
    const float* c1_w  = (const float*)d_in[7];
    const float* c1_b  = (const float*)d_in[8];
    const float* c2_w  = (const float*)d_in[9];
    const float* c2_b  = (const float*)d_in[10];
    const float* fg_lw = (const float*)d_in[11];
    const float* fg_lb = (const float*)d_in[12];
    const float* fg_gw = (const float*)d_in[13];
    const float* fg_gb = (const float*)d_in[14];
    const float* out_w = (const float*)d_in[15];
    const float* out_b = (const float*)d_in[16];
    float* out = (float*)d_out;

    // workspace layout
    float* base = (float*)d_ws;
    const size_t TENS = (size_t)NN * HID;
    float* buf0 = base;                         // h, later A2/x2
    float* buf1 = base + TENS;                  // A1/x1
    float* buf2 = base + 2 * TENS;              // B1/B2
    int*   nbr  = (int*)(base + 3 * TENS);      // NN*16 ints
    float* partM = (float*)(nbr + (size_t)NN * KNN);
    float* partS = partM + 1024 * 256;
    f16* gfrag = (f16*)(partS + 1024 * 256);    // 16384 f16
    f16* f1 = gfrag + 16384;                    // 32768 f16
    f16* f2 = f1 + 32768;                       // 32768 f16

    k_prep<<<320, 256, 0, stream>>>(ig_lw, ig_gw, c1_w, c2_w, gfrag, f1, f2);
    k_glum<<<NN / 64, 256, 0, stream>>>(x, te_w, te_b, (const f16x8*)gfrag,
                                        ig_lb, ig_gb, buf0);
    k_topk<<<NG, 1024, 0, stream>>>(x, nbr);
    // conv1: A1->buf1, B1->buf2 ; x1 = in-place buf1
    k_dualm<<<NN / 64, 256, 0, stream>>>(buf0, (const f16x8*)f1, c1_b, buf1, buf2);
    k_gather<<<(NN * HID) / 256, 256, 0, stream>>>(buf1, buf2, nbr, buf1);
    // conv2: A2->buf0, B2->buf2 ; x2 = in-place buf0
    k_dualm<<<NN / 64, 256, 0, stream>>>(buf1, (const f16x8*)f2, c2_b, buf0, buf2);
    k_gather<<<(NN * HID) / 256, 256, 0, stream>>>(buf0, buf2, nbr, buf0);

    k_pool<<<NG * 16, 256, 0, stream>>>(buf1, buf0, partM, partS);
    k_final<<<NG, 256, 0, stream>>>(partM, partS, fg_lw, fg_lb, fg_gw, fg_gb,
                                    out_w, out_b, out);
}

// Round 4
// 127.108 us; speedup vs baseline: 2.2631x; 1.6343x over previous
//
#include <hip/hip_runtime.h>
#include <math.h>

#define NN 65536
#define NG 64
#define NPG 1024
#define HID 128
#define KNN 16
#define BINF 1e30f

typedef unsigned long long ull;
typedef _Float16 f16;
typedef _Float16 f16x2 __attribute__((ext_vector_type(2)));
typedef _Float16 f16x8 __attribute__((ext_vector_type(8)));
typedef float f32x4 __attribute__((ext_vector_type(4)));

// ---------------------------------------------------------------- weight prep
// frag[mat][kt][nt][lane][i] = M[kt*32 + (lane>>4)*8 + i][nt*16 + (lane&15)]
__global__ __launch_bounds__(256) void k_prep(
    const float* __restrict__ ig_lw, const float* __restrict__ ig_gw,
    const float* __restrict__ c1_w, const float* __restrict__ c2_w,
    f16* __restrict__ gfrag, f16* __restrict__ f1, f16* __restrict__ f2) {
    int gid = blockIdx.x * 256 + threadIdx.x;   // [0, 81920)
    if (gid < 16384) {
        int i = gid & 7, lane = (gid >> 3) & 63, nt = (gid >> 9) & 7;
        int kt = (gid >> 12) & 1, mat = gid >> 13;
        int k = kt * 32 + ((lane >> 4) << 3) + i;
        int c = nt * 16 + (lane & 15);
        float v = 0.0f;
        if (k < 48) v = (mat ? ig_gw : ig_lw)[k * 128 + c];
        gfrag[gid] = (f16)v;
    } else {
        int g2 = gid - 16384;
        int buf = g2 >> 15;
        int rem = g2 & 32767;
        int mat = rem >> 14;
        int r2 = rem & 16383;
        int i = r2 & 7, lane = (r2 >> 3) & 63, nt = (r2 >> 9) & 7, kt = (r2 >> 12) & 3;
        int k = kt * 32 + ((lane >> 4) << 3) + i;
        int c = nt * 16 + (lane & 15);
        const float* cw = buf ? c2_w : c1_w;
        float top = cw[k * 128 + c];
        float bot = cw[(128 + k) * 128 + c];
        float v = mat ? bot : (top - bot);
        (buf ? f2 : f1)[rem] = (f16)v;
    }
}

// ---------------------------------------------------------------- temporal kNN
// Sort per graph; emit sidxg (rank -> global node) and per-rank int8 offsets.
__global__ __launch_bounds__(1024) void k_topk(const float* __restrict__ x,
                                               int* __restrict__ sidxg,
                                               signed char* __restrict__ nbroff) {
    __shared__ ull key[1024];
    __shared__ float st[1024];
    __shared__ int sidx[1024];
    int i = threadIdx.x;
    int g = blockIdx.x;
    float t = x[(size_t)(g * NPG + i) * 17];
    unsigned ub = __float_as_uint(t);
    ub = (ub & 0x80000000u) ? ~ub : (ub | 0x80000000u);   // order-preserving map
    key[i] = ((ull)ub << 32) | (unsigned)i;

    for (int k = 2; k <= 1024; k <<= 1) {
        for (int j = k >> 1; j > 0; j >>= 1) {
            __syncthreads();
            int ixj = i ^ j;
            if (ixj > i) {
                ull a = key[i], b = key[ixj];
                bool up = ((i & k) == 0);
                if ((a > b) == up) { key[i] = b; key[ixj] = a; }
            }
        }
    }
    __syncthreads();
    int oi = (int)(key[i] & 0xffffffffu);
    st[i] = x[(size_t)(g * NPG + oi) * 17];
    sidx[i] = oi;
    sidxg[g * NPG + i] = g * NPG + oi;
    __syncthreads();

    // two-pointer merge in rank space; offsets in [-16,16]
    float tt = st[i];
    int L = i - 1, R = i + 1;
    signed char* out = nbroff + (size_t)(g * NPG + i) * KNN;
#pragma unroll
    for (int q = 0; q < KNN; q++) {
        float dl = (L >= 0)   ? (tt - st[L]) : BINF;
        float dr = (R < NPG) ? (st[R] - tt) : BINF;
        bool left;
        if (dl < dr) left = true;
        else if (dr < dl) left = false;
        else left = (sidx[L] < sidx[R]);   // tie: lower original index (lax.top_k)
        int jr;
        if (left) { jr = L; L--; }
        else      { jr = R; R++; }
        out[q] = (signed char)(jr - i);
    }
}

// ---------------------------------------------------------------- MFMA GLU (rank-order)
__global__ __launch_bounds__(256) void k_glum(
    const float* __restrict__ x, const float* __restrict__ te_w,
    const float* __restrict__ te_b, const f16x8* __restrict__ wfrag,
    const float* __restrict__ bl, const float* __restrict__ bg,
    const int* __restrict__ sidxg, f16* __restrict__ H) {
    __shared__ f16x8 XL[4 * 2 * 64];          // [mf][kt][lane]
    int tid = threadIdx.x;
    int r0 = blockIdx.x * 64;
#pragma unroll
    for (int p = 0; p < 2; p++) {
        int idx = tid + p * 256;              // [0,512)
        int row = idx >> 3, kq = idx & 7;
        int node = sidxg[r0 + row];
        f16x8 h;
        if (kq < 2) {
            const float* xr = x + (size_t)node * 17 + 1 + kq * 8;
#pragma unroll
            for (int i = 0; i < 8; i++) h[i] = (f16)xr[i];
        } else if (kq < 6) {
            float t = x[(size_t)node * 17];
            int j0 = (kq - 2) * 8;
#pragma unroll
            for (int i = 0; i < 8; i++) h[i] = (f16)fmaf(t, te_w[j0 + i], te_b[j0 + i]);
        } else {
#pragma unroll
            for (int i = 0; i < 8; i++) h[i] = (f16)0.0f;
        }
        int mf = row >> 4, kt = kq >> 2, lane = ((kq & 3) << 4) | (row & 15);
        XL[(mf * 2 + kt) * 64 + lane] = h;
    }
    __syncthreads();
    int w = tid >> 6, lane = tid & 63;
    f32x4 acc[2][2][4];
#pragma unroll
    for (int o = 0; o < 2; o++)
#pragma unroll
        for (int j = 0; j < 2; j++)
#pragma unroll
            for (int mf = 0; mf < 4; mf++) acc[o][j][mf] = (f32x4){0.f, 0.f, 0.f, 0.f};
#pragma unroll 1
    for (int kt = 0; kt < 2; kt++) {
        f16x8 wf0[2], wf1[2], xa[4];
#pragma unroll
        for (int j = 0; j < 2; j++) {
            wf0[j] = wfrag[((0 * 2 + kt) * 8 + (w * 2 + j)) * 64 + lane];
            wf1[j] = wfrag[((1 * 2 + kt) * 8 + (w * 2 + j)) * 64 + lane];
        }
#pragma unroll
        for (int mf = 0; mf < 4; mf++) xa[mf] = XL[(mf * 2 + kt) * 64 + lane];
#pragma unroll
        for (int mf = 0; mf < 4; mf++)
#pragma unroll
            for (int j = 0; j < 2; j++) {
                acc[0][j][mf] = __builtin_amdgcn_mfma_f32_16x16x32_f16(xa[mf], wf0[j], acc[0][j][mf], 0, 0, 0);
                acc[1][j][mf] = __builtin_amdgcn_mfma_f32_16x16x32_f16(xa[mf], wf1[j], acc[1][j][mf], 0, 0, 0);
            }
    }
#pragma unroll
    for (int j = 0; j < 2; j++) {
        int col = w * 32 + j * 16 + (lane & 15);
        float bbl = bl[col], bbg = bg[col];
#pragma unroll
        for (int mf = 0; mf < 4; mf++) {
            int rbase = r0 + mf * 16 + ((lane >> 4) << 2);
#pragma unroll
            for (int q = 0; q < 4; q++) {
                float lin = acc[0][j][mf][q] + bbl;
                float gat = acc[1][j][mf][q] + bbg;
                H[(size_t)(rbase + q) * 128 + col] = (f16)(lin / (1.0f + expf(-gat)));
            }
        }
    }
}

// ---------------------------------------------------------------- conv1 dual GEMM
// A = H @ W1 + bias ; B = H @ W2  (all f16 I/O, rank order)
__global__ __launch_bounds__(256) void k_dualm(
    const f16* __restrict__ H, const f16x8* __restrict__ wfrag,
    const float* __restrict__ cb, f16* __restrict__ A, f16* __restrict__ B) {
    __shared__ f16x8 XL[4 * 4 * 64];
    int tid = threadIdx.x;
    int r0 = blockIdx.x * 64;
#pragma unroll
    for (int p = 0; p < 4; p++) {
        int idx = tid + p * 256;              // [0,1024)
        int row = idx >> 4, kq = idx & 15;
        f16x8 h = *(const f16x8*)(H + (size_t)(r0 + row) * 128 + kq * 8);
        int mf = row >> 4, kt = kq >> 2, lane = ((kq & 3) << 4) | (row & 15);
        XL[(mf * 4 + kt) * 64 + lane] = h;
    }
    __syncthreads();
    int w = tid >> 6, lane = tid & 63;
    f32x4 acc[2][2][4];
#pragma unroll
    for (int o = 0; o < 2; o++)
#pragma unroll
        for (int j = 0; j < 2; j++)
#pragma unroll
            for (int mf = 0; mf < 4; mf++) acc[o][j][mf] = (f32x4){0.f, 0.f, 0.f, 0.f};
#pragma unroll 1
    for (int kt = 0; kt < 4; kt++) {
        f16x8 wf0[2], wf1[2], xa[4];
#pragma unroll
        for (int j = 0; j < 2; j++) {
            wf0[j] = wfrag[((0 * 4 + kt) * 8 + (w * 2 + j)) * 64 + lane];
            wf1[j] = wfrag[((1 * 4 + kt) * 8 + (w * 2 + j)) * 64 + lane];
        }
#pragma unroll
        for (int mf = 0; mf < 4; mf++) xa[mf] = XL[(mf * 4 + kt) * 64 + lane];
#pragma unroll
        for (int mf = 0; mf < 4; mf++)
#pragma unroll
            for (int j = 0; j < 2; j++) {
                acc[0][j][mf] = __builtin_amdgcn_mfma_f32_16x16x32_f16(xa[mf], wf0[j], acc[0][j][mf], 0, 0, 0);
                acc[1][j][mf] = __builtin_amdgcn_mfma_f32_16x16x32_f16(xa[mf], wf1[j], acc[1][j][mf], 0, 0, 0);
            }
    }
#pragma unroll
    for (int j = 0; j < 2; j++) {
        int col = w * 32 + j * 16 + (lane & 15);
        float bias = cb[col];
#pragma unroll
        for (int mf = 0; mf < 4; mf++) {
            int rbase = r0 + mf * 16 + ((lane >> 4) << 2);
#pragma unroll
            for (int q = 0; q < 4; q++) {
                A[(size_t)(rbase + q) * 128 + col] = (f16)(acc[0][j][mf][q] + bias);
                B[(size_t)(rbase + q) * 128 + col] = (f16)acc[1][j][mf][q];
            }
        }
    }
}

// ---------------------------------------------------------------- conv2 fused
// x1 = relu(A1 + window-max B1); then A2 = x1@W1'+b, B2 = x1@W2' (MFMA).
__global__ __launch_bounds__(256) void k_conv2f(
    const f16* __restrict__ A1, const f16* __restrict__ B1,
    const signed char* __restrict__ nbroff, const f16x8* __restrict__ wfrag,
    const float* __restrict__ cb, f16* __restrict__ x1,
    f16* __restrict__ A2, f16* __restrict__ B2) {
    __shared__ f16 Bwin[96 * 128];            // rank window [r0-16, r0+80)
    __shared__ f16 x1t[64 * 128];             // XOR-swizzled GEMM input tile
    int tid = threadIdx.x;
    int bx = blockIdx.x;
    int r0 = bx * 64;
    int r0loc = (bx & 15) * 64;
#pragma unroll
    for (int p = 0; p < 6; p++) {
        int idx = tid + p * 256;              // [0,1536)
        int row = idx >> 4, kq = idx & 15;
        int gl = r0loc - 16 + row;
        f16x8 v;
#pragma unroll
        for (int i = 0; i < 8; i++) v[i] = (f16)0.0f;
        if (gl >= 0 && gl < NPG)
            v = *(const f16x8*)(B1 + (size_t)(r0 - 16 + row) * 128 + kq * 8);
        *(f16x8*)&Bwin[row * 128 + kq * 8] = v;
    }
    __syncthreads();
    int w = tid >> 6, lane = tid & 63;
    int c0 = lane * 2;
    for (int rr = 0; rr < 16; rr++) {
        int row = w * 16 + rr;
        int grow = r0 + row;
        int4 ov = *(const int4*)(nbroff + (size_t)grow * 16);
        const int* ow = (const int*)&ov;
        f16x2 av = *(const f16x2*)(A1 + (size_t)grow * 128 + c0);
        float m0 = -BINF, m1 = -BINF;
#pragma unroll
        for (int q = 0; q < 16; q++) {
            int off = (int)(signed char)((ow[q >> 2] >> ((q & 3) * 8)) & 0xff);
            f16x2 bv = *(const f16x2*)&Bwin[(row + 16 + off) * 128 + c0];
            m0 = fmaxf(m0, (float)bv[0]);
            m1 = fmaxf(m1, (float)bv[1]);
        }
        float v0 = fmaxf((float)av[0] + m0, 0.0f);
        float v1 = fmaxf((float)av[1] + m1, 0.0f);
        f16x2 xv; xv[0] = (f16)v0; xv[1] = (f16)v1;
        *(f16x2*)&x1t[(row * 128 + c0) ^ ((row & 7) << 3)] = xv;
        *(f16x2*)(x1 + (size_t)grow * 128 + c0) = xv;
    }
    __syncthreads();
    f32x4 acc[2][2][4];
#pragma unroll
    for (int o = 0; o < 2; o++)
#pragma unroll
        for (int j = 0; j < 2; j++)
#pragma unroll
            for (int mf = 0; mf < 4; mf++) acc[o][j][mf] = (f32x4){0.f, 0.f, 0.f, 0.f};
    int row16 = lane & 15, kslot = lane >> 4;
    int swz = (row16 & 7) << 3;
#pragma unroll 1
    for (int kt = 0; kt < 4; kt++) {
        f16x8 wf0[2], wf1[2], xa[4];
#pragma unroll
        for (int j = 0; j < 2; j++) {
            wf0[j] = wfrag[((0 * 4 + kt) * 8 + (w * 2 + j)) * 64 + lane];
            wf1[j] = wfrag[((1 * 4 + kt) * 8 + (w * 2 + j)) * 64 + lane];
        }
#pragma unroll
        for (int mf = 0; mf < 4; mf++)
            xa[mf] = *(const f16x8*)&x1t[((mf * 16 + row16) * 128 + kt * 32 + kslot * 8) ^ swz];
#pragma unroll
        for (int mf = 0; mf < 4; mf++)
#pragma unroll
            for (int j = 0; j < 2; j++) {
                acc[0][j][mf] = __builtin_amdgcn_mfma_f32_16x16x32_f16(xa[mf], wf0[j], acc[0][j][mf], 0, 0, 0);
                acc[1][j][mf] = __builtin_amdgcn_mfma_f32_16x16x32_f16(xa[mf], wf1[j], acc[1][j][mf], 0, 0, 0);
            }
    }
#pragma unroll
    for (int j = 0; j < 2; j++) {
        int col = w * 32 + j * 16 + (lane & 15);
        float bias = cb[col];
#pragma unroll
        for (int mf = 0; mf < 4; mf++) {
            int rbase = r0 + mf * 16 + ((lane >> 4) << 2);
#pragma unroll
            for (int q = 0; q < 4; q++) {
                A2[(size_t)(rbase + q) * 128 + col] = (f16)(acc[0][j][mf][q] + bias);
                B2[(size_t)(rbase + q) * 128 + col] = (f16)acc[1][j][mf][q];
            }
        }
    }
}

// ---------------------------------------------------------------- gather2 + pool
// x2 rows computed in-register from A2 + window-max B2; never written to HBM.
__global__ __launch_bounds__(256) void k_gather2p(
    const f16* __restrict__ A2, const f16* __restrict__ B2,
    const f16* __restrict__ x1, const signed char* __restrict__ nbroff,
    float* __restrict__ partM, float* __restrict__ partS) {
    __shared__ f16 Bwin[96 * 128];
    __shared__ float red[4 * 64 * 8];
    int tid = threadIdx.x;
    int bx = blockIdx.x;
    int r0 = bx * 64;
    int r0loc = (bx & 15) * 64;
#pragma unroll
    for (int p = 0; p < 6; p++) {
        int idx = tid + p * 256;
        int row = idx >> 4, kq = idx & 15;
        int gl = r0loc - 16 + row;
        f16x8 v;
#pragma unroll
        for (int i = 0; i < 8; i++) v[i] = (f16)0.0f;
        if (gl >= 0 && gl < NPG)
            v = *(const f16x8*)(B2 + (size_t)(r0 - 16 + row) * 128 + kq * 8);
        *(f16x8*)&Bwin[row * 128 + kq * 8] = v;
    }
    __syncthreads();
    int w = tid >> 6, lane = tid & 63;
    int c0 = lane * 2;
    float m1a = -BINF, m1b = -BINF, s1a = 0.f, s1b = 0.f;
    float m2a = -BINF, m2b = -BINF, s2a = 0.f, s2b = 0.f;
    for (int rr = 0; rr < 16; rr++) {
        int row = w * 16 + rr;
        int grow = r0 + row;
        int4 ov = *(const int4*)(nbroff + (size_t)grow * 16);
        const int* ow = (const int*)&ov;
        f16x2 av = *(const f16x2*)(A2 + (size_t)grow * 128 + c0);
        float m0 = -BINF, m1 = -BINF;
#pragma unroll
        for (int q = 0; q < 16; q++) {
            int off = (int)(signed char)((ow[q >> 2] >> ((q & 3) * 8)) & 0xff);
            f16x2 bv = *(const f16x2*)&Bwin[(row + 16 + off) * 128 + c0];
            m0 = fmaxf(m0, (float)bv[0]);
            m1 = fmaxf(m1, (float)bv[1]);
        }
        float v0 = fmaxf((float)av[0] + m0, 0.0f);
        float v1 = fmaxf((float)av[1] + m1, 0.0f);
        m2a = fmaxf(m2a, v0); s2a += v0;
        m2b = fmaxf(m2b, v1); s2b += v1;
        f16x2 xv = *(const f16x2*)(x1 + (size_t)grow * 128 + c0);
        float u0 = (float)xv[0], u1 = (float)xv[1];
        m1a = fmaxf(m1a, u0); s1a += u0;
        m1b = fmaxf(m1b, u1); s1b += u1;
    }
    int rb = (w * 64 + lane) * 8;
    red[rb + 0] = m1a; red[rb + 1] = s1a; red[rb + 2] = m2a; red[rb + 3] = s2a;
    red[rb + 4] = m1b; red[rb + 5] = s1b; red[rb + 6] = m2b; red[rb + 7] = s2b;
    __syncthreads();
    if (tid < 128) {
        int l2 = tid >> 1, j = tid & 1;
        float M1 = -BINF, S1 = 0.f, M2 = -BINF, S2 = 0.f;
#pragma unroll
        for (int w2 = 0; w2 < 4; w2++) {
            int b2 = (w2 * 64 + l2) * 8 + j * 4;
            M1 = fmaxf(M1, red[b2 + 0]); S1 += red[b2 + 1];
            M2 = fmaxf(M2, red[b2 + 2]); S2 += red[b2 + 3];
        }
        size_t ob = (size_t)bx * 256;
        partM[ob + tid] = M1;        partS[ob + tid] = S1;
        partM[ob + 128 + tid] = M2;  partS[ob + 128 + tid] = S2;
    }
}

// ---------------------------------------------------------------- final head
__global__ __launch_bounds__(256) void k_final(const float* __restrict__ partM,
                                               const float* __restrict__ partS,
                                               const float* __restrict__ fg_lw,
                                               const float* __restrict__ fg_lb,
                                               const float* __restrict__ fg_gw,
                                               const float* __restrict__ fg_gb,
                                               const float* __restrict__ out_w,
                                               const float* __restrict__ out_b,
                                               float* __restrict__ out) {
    __shared__ float pooled[512];
    __shared__ float linv[128], gatev[128];
    __shared__ float gluv[128];
    __shared__ float lg[2];
    int g = blockIdx.x, tid = threadIdx.x;

    float mx = -BINF, sm = 0.0f;
    for (int ch = 0; ch < 16; ch++) {
        mx = fmaxf(mx, partM[(size_t)(g * 16 + ch) * 256 + tid]);
        sm += partS[(size_t)(g * 16 + ch) * 256 + tid];
    }
    pooled[tid] = mx;
    pooled[256 + tid] = sm * (1.0f / 1024.0f);
    __syncthreads();

    float acc = 0.0f;
    if (tid < 128) {
        for (int k = 0; k < 512; k++) acc = fmaf(pooled[k], fg_lw[k * 128 + tid], acc);
        linv[tid] = acc + fg_lb[tid];
    } else {
        int c = tid - 128;
        for (int k = 0; k < 512; k++) acc = fmaf(pooled[k], fg_gw[k * 128 + c], acc);
        gatev[c] = acc + fg_gb[c];
    }
    __syncthreads();
    if (tid < 128) gluv[tid] = linv[tid] / (1.0f + expf(-gatev[tid]));
    __syncthreads();
    if (tid < 2) {
        float s = out_b[tid];
        for (int c = 0; c < 128; c++) s = fmaf(gluv[c], out_w[c * 2 + tid], s);
        lg[tid] = s;
    }
    __syncthreads();
    if (tid < 2) {
        float m = fmaxf(lg[0], lg[1]);
        float lse = m + logf(expf(lg[0] - m) + expf(lg[1] - m));
        out[g * 2 + tid] = lg[tid] - lse;
    }
}

// ---------------------------------------------------------------- launch
extern "C" void kernel_launch(void* const* d_in, const int* in_sizes, int n_in,
                              void* d_out, int out_size, void* d_ws, size_t ws_size,
                              hipStream_t stream) {
    const float* x     = (const float*)d_in[0];
    const float* te_w  = (const float*)d_in[1];
    const float* te_b  = (const float*)d_in[2];
    const float* ig_lw = (const float*)d_in[3];
    const float* ig_lb = (const float*)d_in[4];
    const float* ig_gw = (const float*)d_in[5];
    const float* ig_gb = (const float*)d_in[6];
    const float* c1_w  = (const float*)d_in[7];
    const float* c1_b  = (const float*)d_in[8];
    const float* c2_w  = (const float*)d_in[9];
    const float* c2_b  = (const float*)d_in[10];
    const float* fg_lw = (const float*)d_in[11];
    const float* fg_lb = (const float*)d_in[12];
    const float* fg_gw = (const float*)d_in[13];
    const float* fg_gb = (const float*)d_in[14];
    const float* out_w = (const float*)d_in[15];
    const float* out_b = (const float*)d_in[16];
    float* out = (float*)d_out;

    // workspace layout (~100 MB)
    char* p = (char*)d_ws;
    const size_t T16 = (size_t)NN * HID * sizeof(f16);   // 16 MB
    f16* H  = (f16*)p; p += T16;
    f16* A1 = (f16*)p; p += T16;
    f16* B1 = (f16*)p; p += T16;
    f16* x1 = (f16*)p; p += T16;
    f16* A2 = (f16*)p; p += T16;
    f16* B2 = (f16*)p; p += T16;
    int* sidxg = (int*)p;            p += (size_t)NN * 4;
    signed char* nbroff = (signed char*)p; p += (size_t)NN * KNN;
    float* partM = (float*)p;        p += (size_t)1024 * 256 * 4;
    float* partS = (float*)p;        p += (size_t)1024 * 256 * 4;
    f16* gfrag = (f16*)p;            p += 16384 * 2;
    f16* f1 = (f16*)p;               p += 32768 * 2;
    f16* f2 = (f16*)p;               p += 32768 * 2;

    k_prep<<<320, 256, 0, stream>>>(ig_lw, ig_gw, c1_w, c2_w, gfrag, f1, f2);
    k_topk<<<NG, 1024, 0, stream>>>(x, sidxg, nbroff);
    k_glum<<<NN / 64, 256, 0, stream>>>(x, te_w, te_b, (const f16x8*)gfrag,
                                        ig_lb, ig_gb, sidxg, H);
    k_dualm<<<NN / 64, 256, 0, stream>>>(H, (const f16x8*)f1, c1_b, A1, B1);
    k_conv2f<<<NN / 64, 256, 0, stream>>>(A1, B1, nbroff, (const f16x8*)f2,
                                          c2_b, x1, A2, B2);
    k_gather2p<<<NN / 64, 256, 0, stream>>>(A2, B2, x1, nbroff, partM, partS);
    k_final<<<NG, 256, 0, stream>>>(partM, partS, fg_lw, fg_lb, fg_gw, fg_gb,
                                    out_w, out_b, out);
}

// Round 5
// 120.098 us; speedup vs baseline: 2.3952x; 1.0584x over previous
//
#include <hip/hip_runtime.h>
#include <math.h>

#define NN 65536
#define NG 64
#define NPG 1024
#define HID 128
#define KNN 16
#define BINF 1e30f

typedef unsigned long long ull;
typedef _Float16 f16;
typedef _Float16 f16x2 __attribute__((ext_vector_type(2)));
typedef _Float16 f16x8 __attribute__((ext_vector_type(8)));
typedef float f32x4 __attribute__((ext_vector_type(4)));

// ---------------------------------------------------------------- weight prep
// frag[mat][kt][nt][lane][i] = M[kt*32 + (lane>>4)*8 + i][nt*16 + (lane&15)]
__global__ __launch_bounds__(256) void k_prep(
    const float* __restrict__ ig_lw, const float* __restrict__ ig_gw,
    const float* __restrict__ c1_w, const float* __restrict__ c2_w,
    f16* __restrict__ gfrag, f16* __restrict__ f1, f16* __restrict__ f2) {
    int gid = blockIdx.x * 256 + threadIdx.x;   // [0, 81920)
    if (gid < 16384) {
        int i = gid & 7, lane = (gid >> 3) & 63, nt = (gid >> 9) & 7;
        int kt = (gid >> 12) & 1, mat = gid >> 13;
        int k = kt * 32 + ((lane >> 4) << 3) + i;
        int c = nt * 16 + (lane & 15);
        float v = 0.0f;
        if (k < 48) v = (mat ? ig_gw : ig_lw)[k * 128 + c];
        gfrag[gid] = (f16)v;
    } else {
        int g2 = gid - 16384;
        int buf = g2 >> 15;
        int rem = g2 & 32767;
        int mat = rem >> 14;
        int r2 = rem & 16383;
        int i = r2 & 7, lane = (r2 >> 3) & 63, nt = (r2 >> 9) & 7, kt = (r2 >> 12) & 3;
        int k = kt * 32 + ((lane >> 4) << 3) + i;
        int c = nt * 16 + (lane & 15);
        const float* cw = buf ? c2_w : c1_w;
        float top = cw[k * 128 + c];
        float bot = cw[(128 + k) * 128 + c];
        float v = mat ? bot : (top - bot);
        (buf ? f2 : f1)[rem] = (f16)v;
    }
}

// ---------------------------------------------------------------- temporal kNN
// Shuffle-bitonic sort (45 intra-wave stages via shfl_xor, 10 cross-wave via LDS)
__global__ __launch_bounds__(1024) void k_topk(const float* __restrict__ x,
                                               int* __restrict__ sidxg,
                                               signed char* __restrict__ nbroff) {
    __shared__ ull key[1024];
    __shared__ float st[1024];
    __shared__ int sidx[1024];
    int i = threadIdx.x;
    int g = blockIdx.x;
    float t = x[(size_t)(g * NPG + i) * 17];
    unsigned ub = __float_as_uint(t);
    ub = (ub & 0x80000000u) ? ~ub : (ub | 0x80000000u);   // order-preserving map
    ull kk = ((ull)ub << 32) | (unsigned)i;

    for (int k = 2; k <= 1024; k <<= 1) {
        for (int j = k >> 1; j > 0; j >>= 1) {
            ull pv;
            if (j >= 64) {
                key[i] = kk;
                __syncthreads();
                pv = key[i ^ j];
                __syncthreads();
            } else {
                pv = __shfl_xor(kk, j, 64);
            }
            bool up = ((i & k) == 0);
            bool low = ((i & j) == 0);
            ull mn = kk < pv ? kk : pv;
            ull mx = kk < pv ? pv : kk;
            kk = (up == low) ? mn : mx;
        }
    }
    int oi = (int)(kk & 0xffffffffu);
    st[i] = x[(size_t)(g * NPG + oi) * 17];
    sidx[i] = oi;
    sidxg[g * NPG + i] = g * NPG + oi;
    __syncthreads();

    // two-pointer merge in rank space; offsets in [-16,16]
    float tt = st[i];
    int L = i - 1, R = i + 1;
    signed char* out = nbroff + (size_t)(g * NPG + i) * KNN;
#pragma unroll
    for (int q = 0; q < KNN; q++) {
        float dl = (L >= 0)   ? (tt - st[L]) : BINF;
        float dr = (R < NPG) ? (st[R] - tt) : BINF;
        bool left;
        if (dl < dr) left = true;
        else if (dr < dl) left = false;
        else left = (sidx[L] < sidx[R]);   // tie: lower original index (lax.top_k)
        int jr;
        if (left) { jr = L; L--; }
        else      { jr = R; R++; }
        out[q] = (signed char)(jr - i);
    }
}

// ---------------------------------------------------------------- fused GLU + conv1
// H tile lives only in LDS; A1 = H@W1+b, B1 = H@W2 written f16 (rank order).
__global__ __launch_bounds__(256) void k_fuse1(
    const float* __restrict__ x, const float* __restrict__ te_w,
    const float* __restrict__ te_b, const f16x8* __restrict__ gfrag,
    const float* __restrict__ bl, const float* __restrict__ bg,
    const int* __restrict__ sidxg, const f16x8* __restrict__ wfrag,
    const float* __restrict__ cb, f16* __restrict__ A, f16* __restrict__ B) {
    __shared__ f16x8 XL[4 * 2 * 64];          // Z fragments [mf][kt][lane]
    __shared__ f16 ht[64 * 128];              // XOR-swizzled H tile
    int tid = threadIdx.x;
    int r0 = blockIdx.x * 64;
#pragma unroll
    for (int p = 0; p < 2; p++) {
        int idx = tid + p * 256;              // [0,512)
        int row = idx >> 3, kq = idx & 7;
        int node = sidxg[r0 + row];
        f16x8 h;
        if (kq < 2) {
            const float* xr = x + (size_t)node * 17 + 1 + kq * 8;
#pragma unroll
            for (int i = 0; i < 8; i++) h[i] = (f16)xr[i];
        } else if (kq < 6) {
            float t = x[(size_t)node * 17];
            int j0 = (kq - 2) * 8;
#pragma unroll
            for (int i = 0; i < 8; i++) h[i] = (f16)fmaf(t, te_w[j0 + i], te_b[j0 + i]);
        } else {
#pragma unroll
            for (int i = 0; i < 8; i++) h[i] = (f16)0.0f;
        }
        int mf = row >> 4, kt = kq >> 2, lane = ((kq & 3) << 4) | (row & 15);
        XL[(mf * 2 + kt) * 64 + lane] = h;
    }
    __syncthreads();
    int w = tid >> 6, lane = tid & 63;
    f32x4 acc[2][2][4];
#pragma unroll
    for (int o = 0; o < 2; o++)
#pragma unroll
        for (int j = 0; j < 2; j++)
#pragma unroll
            for (int mf = 0; mf < 4; mf++) acc[o][j][mf] = (f32x4){0.f, 0.f, 0.f, 0.f};
#pragma unroll 1
    for (int kt = 0; kt < 2; kt++) {
        f16x8 wf0[2], wf1[2], xa[4];
#pragma unroll
        for (int j = 0; j < 2; j++) {
            wf0[j] = gfrag[((0 * 2 + kt) * 8 + (w * 2 + j)) * 64 + lane];
            wf1[j] = gfrag[((1 * 2 + kt) * 8 + (w * 2 + j)) * 64 + lane];
        }
#pragma unroll
        for (int mf = 0; mf < 4; mf++) xa[mf] = XL[(mf * 2 + kt) * 64 + lane];
#pragma unroll
        for (int mf = 0; mf < 4; mf++)
#pragma unroll
            for (int j = 0; j < 2; j++) {
                acc[0][j][mf] = __builtin_amdgcn_mfma_f32_16x16x32_f16(xa[mf], wf0[j], acc[0][j][mf], 0, 0, 0);
                acc[1][j][mf] = __builtin_amdgcn_mfma_f32_16x16x32_f16(xa[mf], wf1[j], acc[1][j][mf], 0, 0, 0);
            }
    }
    // GLU epilogue -> swizzled LDS tile
#pragma unroll
    for (int j = 0; j < 2; j++) {
        int col = w * 32 + j * 16 + (lane & 15);
        float bbl = bl[col], bbg = bg[col];
#pragma unroll
        for (int mf = 0; mf < 4; mf++) {
            int rloc = mf * 16 + ((lane >> 4) << 2);
#pragma unroll
            for (int q = 0; q < 4; q++) {
                float lin = acc[0][j][mf][q] + bbl;
                float gat = acc[1][j][mf][q] + bbg;
                int row = rloc + q;
                ht[(row * 128 + col) ^ ((row & 7) << 3)] = (f16)(lin / (1.0f + expf(-gat)));
            }
        }
    }
    __syncthreads();
    // conv1 dual GEMM from ht
#pragma unroll
    for (int o = 0; o < 2; o++)
#pragma unroll
        for (int j = 0; j < 2; j++)
#pragma unroll
            for (int mf = 0; mf < 4; mf++) acc[o][j][mf] = (f32x4){0.f, 0.f, 0.f, 0.f};
    int row16 = lane & 15, kslot = lane >> 4;
    int swz = (row16 & 7) << 3;
#pragma unroll 1
    for (int kt = 0; kt < 4; kt++) {
        f16x8 wf0[2], wf1[2], xa[4];
#pragma unroll
        for (int j = 0; j < 2; j++) {
            wf0[j] = wfrag[((0 * 4 + kt) * 8 + (w * 2 + j)) * 64 + lane];
            wf1[j] = wfrag[((1 * 4 + kt) * 8 + (w * 2 + j)) * 64 + lane];
        }
#pragma unroll
        for (int mf = 0; mf < 4; mf++)
            xa[mf] = *(const f16x8*)&ht[((mf * 16 + row16) * 128 + kt * 32 + kslot * 8) ^ swz];
#pragma unroll
        for (int mf = 0; mf < 4; mf++)
#pragma unroll
            for (int j = 0; j < 2; j++) {
                acc[0][j][mf] = __builtin_amdgcn_mfma_f32_16x16x32_f16(xa[mf], wf0[j], acc[0][j][mf], 0, 0, 0);
                acc[1][j][mf] = __builtin_amdgcn_mfma_f32_16x16x32_f16(xa[mf], wf1[j], acc[1][j][mf], 0, 0, 0);
            }
    }
#pragma unroll
    for (int j = 0; j < 2; j++) {
        int col = w * 32 + j * 16 + (lane & 15);
        float bias = cb[col];
#pragma unroll
        for (int mf = 0; mf < 4; mf++) {
            int rbase = r0 + mf * 16 + ((lane >> 4) << 2);
#pragma unroll
            for (int q = 0; q < 4; q++) {
                A[(size_t)(rbase + q) * 128 + col] = (f16)(acc[0][j][mf][q] + bias);
                B[(size_t)(rbase + q) * 128 + col] = (f16)acc[1][j][mf][q];
            }
        }
    }
}

// ---------------------------------------------------------------- conv2 fused
// x1 = relu(A1 + window-max B1) (LDS only); pool x1 partials; A2/B2 = x1@W'.
__global__ __launch_bounds__(256) void k_conv2f(
    const f16* __restrict__ A1, const f16* __restrict__ B1,
    const signed char* __restrict__ nbroff, const f16x8* __restrict__ wfrag,
    const float* __restrict__ cb, f16* __restrict__ A2, f16* __restrict__ B2,
    float* __restrict__ partM1, float* __restrict__ partS1) {
    __shared__ f16 Bwin[96 * 128];            // rank window [r0-16, r0+80)
    __shared__ f16 x1t[64 * 128];             // XOR-swizzled GEMM input tile
    __shared__ float redM[4 * 128];
    __shared__ float redS[4 * 128];
    int tid = threadIdx.x;
    int bx = blockIdx.x;
    int r0 = bx * 64;
    int r0loc = (bx & 15) * 64;
#pragma unroll
    for (int p = 0; p < 6; p++) {
        int idx = tid + p * 256;              // [0,1536)
        int row = idx >> 4, kq = idx & 15;
        int gl = r0loc - 16 + row;
        f16x8 v;
#pragma unroll
        for (int i = 0; i < 8; i++) v[i] = (f16)0.0f;
        if (gl >= 0 && gl < NPG)
            v = *(const f16x8*)(B1 + (size_t)(r0 - 16 + row) * 128 + kq * 8);
        *(f16x8*)&Bwin[row * 128 + kq * 8] = v;
    }
    __syncthreads();
    int w = tid >> 6, lane = tid & 63;
    int c0 = lane * 2;
    float m1a = -BINF, m1b = -BINF, s1a = 0.f, s1b = 0.f;
    for (int rr = 0; rr < 16; rr++) {
        int row = w * 16 + rr;
        int grow = r0 + row;
        int4 ov = *(const int4*)(nbroff + (size_t)grow * 16);
        const int* ow = (const int*)&ov;
        f16x2 av = *(const f16x2*)(A1 + (size_t)grow * 128 + c0);
        float m0 = -BINF, m1 = -BINF;
#pragma unroll
        for (int q = 0; q < 16; q++) {
            int off = (int)(signed char)((ow[q >> 2] >> ((q & 3) * 8)) & 0xff);
            f16x2 bv = *(const f16x2*)&Bwin[(row + 16 + off) * 128 + c0];
            m0 = fmaxf(m0, (float)bv[0]);
            m1 = fmaxf(m1, (float)bv[1]);
        }
        float v0 = fmaxf((float)av[0] + m0, 0.0f);
        float v1 = fmaxf((float)av[1] + m1, 0.0f);
        m1a = fmaxf(m1a, v0); s1a += v0;
        m1b = fmaxf(m1b, v1); s1b += v1;
        f16x2 xv; xv[0] = (f16)v0; xv[1] = (f16)v1;
        *(f16x2*)&x1t[(row * 128 + c0) ^ ((row & 7) << 3)] = xv;
    }
    redM[w * 128 + c0] = m1a; redM[w * 128 + c0 + 1] = m1b;
    redS[w * 128 + c0] = s1a; redS[w * 128 + c0 + 1] = s1b;
    __syncthreads();
    if (tid < 128) {
        float M = -BINF, S = 0.f;
#pragma unroll
        for (int w2 = 0; w2 < 4; w2++) {
            M = fmaxf(M, redM[w2 * 128 + tid]);
            S += redS[w2 * 128 + tid];
        }
        partM1[(size_t)bx * 128 + tid] = M;
        partS1[(size_t)bx * 128 + tid] = S;
    }
    f32x4 acc[2][2][4];
#pragma unroll
    for (int o = 0; o < 2; o++)
#pragma unroll
        for (int j = 0; j < 2; j++)
#pragma unroll
            for (int mf = 0; mf < 4; mf++) acc[o][j][mf] = (f32x4){0.f, 0.f, 0.f, 0.f};
    int row16 = lane & 15, kslot = lane >> 4;
    int swz = (row16 & 7) << 3;
#pragma unroll 1
    for (int kt = 0; kt < 4; kt++) {
        f16x8 wf0[2], wf1[2], xa[4];
#pragma unroll
        for (int j = 0; j < 2; j++) {
            wf0[j] = wfrag[((0 * 4 + kt) * 8 + (w * 2 + j)) * 64 + lane];
            wf1[j] = wfrag[((1 * 4 + kt) * 8 + (w * 2 + j)) * 64 + lane];
        }
#pragma unroll
        for (int mf = 0; mf < 4; mf++)
            xa[mf] = *(const f16x8*)&x1t[((mf * 16 + row16) * 128 + kt * 32 + kslot * 8) ^ swz];
#pragma unroll
        for (int mf = 0; mf < 4; mf++)
#pragma unroll
            for (int j = 0; j < 2; j++) {
                acc[0][j][mf] = __builtin_amdgcn_mfma_f32_16x16x32_f16(xa[mf], wf0[j], acc[0][j][mf], 0, 0, 0);
                acc[1][j][mf] = __builtin_amdgcn_mfma_f32_16x16x32_f16(xa[mf], wf1[j], acc[1][j][mf], 0, 0, 0);
            }
    }
#pragma unroll
    for (int j = 0; j < 2; j++) {
        int col = w * 32 + j * 16 + (lane & 15);
        float bias = cb[col];
#pragma unroll
        for (int mf = 0; mf < 4; mf++) {
            int rbase = r0 + mf * 16 + ((lane >> 4) << 2);
#pragma unroll
            for (int q = 0; q < 4; q++) {
                A2[(size_t)(rbase + q) * 128 + col] = (f16)(acc[0][j][mf][q] + bias);
                B2[(size_t)(rbase + q) * 128 + col] = (f16)acc[1][j][mf][q];
            }
        }
    }
}

// ---------------------------------------------------------------- gather2 + pool
__global__ __launch_bounds__(256) void k_gather2p(
    const f16* __restrict__ A2, const f16* __restrict__ B2,
    const signed char* __restrict__ nbroff,
    float* __restrict__ partM2, float* __restrict__ partS2) {
    __shared__ f16 Bwin[96 * 128];
    __shared__ float redM[4 * 128];
    __shared__ float redS[4 * 128];
    int tid = threadIdx.x;
    int bx = blockIdx.x;
    int r0 = bx * 64;
    int r0loc = (bx & 15) * 64;
#pragma unroll
    for (int p = 0; p < 6; p++) {
        int idx = tid + p * 256;
        int row = idx >> 4, kq = idx & 15;
        int gl = r0loc - 16 + row;
        f16x8 v;
#pragma unroll
        for (int i = 0; i < 8; i++) v[i] = (f16)0.0f;
        if (gl >= 0 && gl < NPG)
            v = *(const f16x8*)(B2 + (size_t)(r0 - 16 + row) * 128 + kq * 8);
        *(f16x8*)&Bwin[row * 128 + kq * 8] = v;
    }
    __syncthreads();
    int w = tid >> 6, lane = tid & 63;
    int c0 = lane * 2;
    float m2a = -BINF, m2b = -BINF, s2a = 0.f, s2b = 0.f;
    for (int rr = 0; rr < 16; rr++) {
        int row = w * 16 + rr;
        int grow = r0 + row;
        int4 ov = *(const int4*)(nbroff + (size_t)grow * 16);
        const int* ow = (const int*)&ov;
        f16x2 av = *(const f16x2*)(A2 + (size_t)grow * 128 + c0);
        float m0 = -BINF, m1 = -BINF;
#pragma unroll
        for (int q = 0; q < 16; q++) {
            int off = (int)(signed char)((ow[q >> 2] >> ((q & 3) * 8)) & 0xff);
            f16x2 bv = *(const f16x2*)&Bwin[(row + 16 + off) * 128 + c0];
            m0 = fmaxf(m0, (float)bv[0]);
            m1 = fmaxf(m1, (float)bv[1]);
        }
        float v0 = fmaxf((float)av[0] + m0, 0.0f);
        float v1 = fmaxf((float)av[1] + m1, 0.0f);
        m2a = fmaxf(m2a, v0); s2a += v0;
        m2b = fmaxf(m2b, v1); s2b += v1;
    }
    redM[w * 128 + c0] = m2a; redM[w * 128 + c0 + 1] = m2b;
    redS[w * 128 + c0] = s2a; redS[w * 128 + c0 + 1] = s2b;
    __syncthreads();
    if (tid < 128) {
        float M = -BINF, S = 0.f;
#pragma unroll
        for (int w2 = 0; w2 < 4; w2++) {
            M = fmaxf(M, redM[w2 * 128 + tid]);
            S += redS[w2 * 128 + tid];
        }
        partM2[(size_t)bx * 128 + tid] = M;
        partS2[(size_t)bx * 128 + tid] = S;
    }
}

// ---------------------------------------------------------------- final head
__global__ __launch_bounds__(256) void k_final(const float* __restrict__ partM1,
                                               const float* __restrict__ partS1,
                                               const float* __restrict__ partM2,
                                               const float* __restrict__ partS2,
                                               const float* __restrict__ fg_lw,
                                               const float* __restrict__ fg_lb,
                                               const float* __restrict__ fg_gw,
                                               const float* __restrict__ fg_gb,
                                               const float* __restrict__ out_w,
                                               const float* __restrict__ out_b,
                                               float* __restrict__ out) {
    __shared__ float pooled[512];
    __shared__ float linv[128], gatev[128];
    __shared__ float gluv[128];
    __shared__ float lg[2];
    int g = blockIdx.x, tid = threadIdx.x;

    const float* pM = (tid < 128) ? partM1 : partM2;
    const float* pS = (tid < 128) ? partS1 : partS2;
    int cc = tid & 127;
    float mx = -BINF, sm = 0.0f;
    for (int ch = 0; ch < 16; ch++) {
        mx = fmaxf(mx, pM[(size_t)(g * 16 + ch) * 128 + cc]);
        sm += pS[(size_t)(g * 16 + ch) * 128 + cc];
    }
    pooled[tid] = mx;
    pooled[256 + tid] = sm * (1.0f / 1024.0f);
    __syncthreads();

    float acc = 0.0f;
    if (tid < 128) {
        for (int k = 0; k < 512; k++) acc = fmaf(pooled[k], fg_lw[k * 128 + tid], acc);
        linv[tid] = acc + fg_lb[tid];
    } else {
        int c = tid - 128;
        for (int k = 0; k < 512; k++) acc = fmaf(pooled[k], fg_gw[k * 128 + c], acc);
        gatev[c] = acc + fg_gb[c];
    }
    __syncthreads();
    if (tid < 128) gluv[tid] = linv[tid] / (1.0f + expf(-gatev[tid]));
    __syncthreads();
    if (tid < 2) {
        float s = out_b[tid];
        for (int c = 0; c < 128; c++) s = fmaf(gluv[c], out_w[c * 2 + tid], s);
        lg[tid] = s;
    }
    __syncthreads();
    if (tid < 2) {
        float m = fmaxf(lg[0], lg[1]);
        float lse = m + logf(expf(lg[0] - m) + expf(lg[1] - m));
        out[g * 2 + tid] = lg[tid] - lse;
    }
}

// ---------------------------------------------------------------- launch
extern "C" void kernel_launch(void* const* d_in, const int* in_sizes, int n_in,
                              void* d_out, int out_size, void* d_ws, size_t ws_size,
                              hipStream_t stream) {
    const float* x     = (const float*)d_in[0];
    const float* te_w  = (const float*)d_in[1];
    const float* te_b  = (const float*)d_in[2];
    const float* ig_lw = (const float*)d_in[3];
    const float* ig_lb = (const float*)d_in[4];
    const float* ig_gw = (const float*)d_in[5];
    const float* ig_gb = (const float*)d_in[6];
    const float* c1_w  = (const float*)d_in[7];
    const float* c1_b  = (const float*)d_in[8];
    const float* c2_w  = (const float*)d_in[9];
    const float* c2_b  = (const float*)d_in[10];
    const float* fg_lw = (const float*)d_in[11];
    const float* fg_lb = (const float*)d_in[12];
    const float* fg_gw = (const float*)d_in[13];
    const float* fg_gb = (const float*)d_in[14];
    const float* out_w = (const float*)d_in[15];
    const float* out_b = (const float*)d_in[16];
    float* out = (float*)d_out;

    // workspace layout (~67 MB)
    char* p = (char*)d_ws;
    const size_t T16 = (size_t)NN * HID * sizeof(f16);   // 16 MB
    f16* A1 = (f16*)p; p += T16;
    f16* B1 = (f16*)p; p += T16;
    f16* A2 = (f16*)p; p += T16;
    f16* B2 = (f16*)p; p += T16;
    int* sidxg = (int*)p;            p += (size_t)NN * 4;
    signed char* nbroff = (signed char*)p; p += (size_t)NN * KNN;
    float* partM1 = (float*)p;       p += (size_t)1024 * 128 * 4;
    float* partS1 = (float*)p;       p += (size_t)1024 * 128 * 4;
    float* partM2 = (float*)p;       p += (size_t)1024 * 128 * 4;
    float* partS2 = (float*)p;       p += (size_t)1024 * 128 * 4;
    f16* gfrag = (f16*)p;            p += 16384 * 2;
    f16* f1 = (f16*)p;               p += 32768 * 2;
    f16* f2 = (f16*)p;               p += 32768 * 2;

    k_prep<<<320, 256, 0, stream>>>(ig_lw, ig_gw, c1_w, c2_w, gfrag, f1, f2);
    k_topk<<<NG, 1024, 0, stream>>>(x, sidxg, nbroff);
    k_fuse1<<<NN / 64, 256, 0, stream>>>(x, te_w, te_b, (const f16x8*)gfrag,
                                         ig_lb, ig_gb, sidxg, (const f16x8*)f1,
                                         c1_b, A1, B1);
    k_conv2f<<<NN / 64, 256, 0, stream>>>(A1, B1, nbroff, (const f16x8*)f2,
                                          c2_b, A2, B2, partM1, partS1);
    k_gather2p<<<NN / 64, 256, 0, stream>>>(A2, B2, nbroff, partM2, partS2);
    k_final<<<NG, 256, 0, stream>>>(partM1, partS1, partM2, partS2,
                                    fg_lw, fg_lb, fg_gw, fg_gb, out_w, out_b, out);
}

// Round 7
// 105.186 us; speedup vs baseline: 2.7347x; 1.1418x over previous
//
#include <hip/hip_runtime.h>
#include <math.h>

#define NN 65536
#define NG 64
#define NPG 1024
#define HID 128
#define KNN 16
#define BINF 1e30f

typedef unsigned long long ull;
typedef _Float16 f16;
typedef _Float16 f16x8 __attribute__((ext_vector_type(8)));
typedef float f32x4 __attribute__((ext_vector_type(4)));

// ---------------------------------------------------------------- kNN sort + weight prep
// blocks [0,64): per-graph shuffle-bitonic sort -> sidxg + int8 rank offsets
// blocks [64,144): fragment-pack fp16 weights (prep), 1024 threads each
__global__ __launch_bounds__(1024) void k_topk(
    const float* __restrict__ x, int* __restrict__ sidxg,
    signed char* __restrict__ nbroff,
    const float* __restrict__ ig_lw, const float* __restrict__ ig_gw,
    const float* __restrict__ c1_w, const float* __restrict__ c2_w,
    f16* __restrict__ gfrag, f16* __restrict__ f1, f16* __restrict__ f2) {
    __shared__ ull key[1024];
    __shared__ float st[1024];
    __shared__ int sidx[1024];
    int g = blockIdx.x;
    if (g >= NG) {
        int gid = (g - NG) * 1024 + threadIdx.x;   // [0, 81920)
        if (gid < 16384) {
            int i = gid & 7, lane = (gid >> 3) & 63, nt = (gid >> 9) & 7;
            int kt = (gid >> 12) & 1, mat = gid >> 13;
            int k = kt * 32 + ((lane >> 4) << 3) + i;
            int c = nt * 16 + (lane & 15);
            float v = 0.0f;
            if (k < 48) v = (mat ? ig_gw : ig_lw)[k * 128 + c];
            gfrag[gid] = (f16)v;
        } else {
            int g2 = gid - 16384;
            int buf = g2 >> 15;
            int rem = g2 & 32767;
            int mat = rem >> 14;
            int r2 = rem & 16383;
            int i = r2 & 7, lane = (r2 >> 3) & 63, nt = (r2 >> 9) & 7, kt = (r2 >> 12) & 3;
            int k = kt * 32 + ((lane >> 4) << 3) + i;
            int c = nt * 16 + (lane & 15);
            const float* cw = buf ? c2_w : c1_w;
            float top = cw[k * 128 + c];
            float bot = cw[(128 + k) * 128 + c];
            float v = mat ? bot : (top - bot);
            (buf ? f2 : f1)[rem] = (f16)v;
        }
        return;
    }
    int i = threadIdx.x;
    float t = x[(size_t)(g * NPG + i) * 17];
    unsigned ub = __float_as_uint(t);
    ub = (ub & 0x80000000u) ? ~ub : (ub | 0x80000000u);   // order-preserving map
    ull kk = ((ull)ub << 32) | (unsigned)i;

    for (int k = 2; k <= 1024; k <<= 1) {
        for (int j = k >> 1; j > 0; j >>= 1) {
            ull pv;
            if (j >= 64) {
                key[i] = kk;
                __syncthreads();
                pv = key[i ^ j];
                __syncthreads();
            } else {
                pv = __shfl_xor(kk, j, 64);
            }
            bool up = ((i & k) == 0);
            bool low = ((i & j) == 0);
            ull mn = kk < pv ? kk : pv;
            ull mx = kk < pv ? pv : kk;
            kk = (up == low) ? mn : mx;
        }
    }
    int oi = (int)(kk & 0xffffffffu);
    st[i] = x[(size_t)(g * NPG + oi) * 17];
    sidx[i] = oi;
    sidxg[g * NPG + i] = g * NPG + oi;
    __syncthreads();

    // two-pointer merge in rank space; offsets in [-16,16]
    float tt = st[i];
    int L = i - 1, R = i + 1;
    signed char* out = nbroff + (size_t)(g * NPG + i) * KNN;
#pragma unroll
    for (int q = 0; q < KNN; q++) {
        float dl = (L >= 0)   ? (tt - st[L]) : BINF;
        float dr = (R < NPG) ? (st[R] - tt) : BINF;
        bool left;
        if (dl < dr) left = true;
        else if (dr < dl) left = false;
        else left = (sidx[L] < sidx[R]);   // tie: lower original index (lax.top_k)
        int jr;
        if (left) { jr = L; L--; }
        else      { jr = R; R++; }
        out[q] = (signed char)(jr - i);
    }
}

// ---------------------------------------------------------------- fused GLU + conv1
// H tile lives only in LDS; A1 = H@W1+b, B1 = H@W2 written f16 (rank order).
__global__ __launch_bounds__(256) void k_fuse1(
    const float* __restrict__ x, const float* __restrict__ te_w,
    const float* __restrict__ te_b, const f16x8* __restrict__ gfrag,
    const float* __restrict__ bl, const float* __restrict__ bg,
    const int* __restrict__ sidxg, const f16x8* __restrict__ wfrag,
    const float* __restrict__ cb, f16* __restrict__ A, f16* __restrict__ B) {
    __shared__ f16x8 XL[4 * 2 * 64];          // Z fragments [mf][kt][lane]
    __shared__ f16 ht[64 * 128];              // XOR-swizzled H tile
    int tid = threadIdx.x;
    int r0 = blockIdx.x * 64;
#pragma unroll
    for (int p = 0; p < 2; p++) {
        int idx = tid + p * 256;              // [0,512)
        int row = idx >> 3, kq = idx & 7;
        int node = sidxg[r0 + row];
        f16x8 h;
        if (kq < 2) {
            const float* xr = x + (size_t)node * 17 + 1 + kq * 8;
#pragma unroll
            for (int i = 0; i < 8; i++) h[i] = (f16)xr[i];
        } else if (kq < 6) {
            float t = x[(size_t)node * 17];
            int j0 = (kq - 2) * 8;
#pragma unroll
            for (int i = 0; i < 8; i++) h[i] = (f16)fmaf(t, te_w[j0 + i], te_b[j0 + i]);
        } else {
#pragma unroll
            for (int i = 0; i < 8; i++) h[i] = (f16)0.0f;
        }
        int mf = row >> 4, kt = kq >> 2, lane = ((kq & 3) << 4) | (row & 15);
        XL[(mf * 2 + kt) * 64 + lane] = h;
    }
    __syncthreads();
    int w = tid >> 6, lane = tid & 63;
    f32x4 acc[2][2][4];
#pragma unroll
    for (int o = 0; o < 2; o++)
#pragma unroll
        for (int j = 0; j < 2; j++)
#pragma unroll
            for (int mf = 0; mf < 4; mf++) acc[o][j][mf] = (f32x4){0.f, 0.f, 0.f, 0.f};
#pragma unroll 1
    for (int kt = 0; kt < 2; kt++) {
        f16x8 wf0[2], wf1[2], xa[4];
#pragma unroll
        for (int j = 0; j < 2; j++) {
            wf0[j] = gfrag[((0 * 2 + kt) * 8 + (w * 2 + j)) * 64 + lane];
            wf1[j] = gfrag[((1 * 2 + kt) * 8 + (w * 2 + j)) * 64 + lane];
        }
#pragma unroll
        for (int mf = 0; mf < 4; mf++) xa[mf] = XL[(mf * 2 + kt) * 64 + lane];
#pragma unroll
        for (int mf = 0; mf < 4; mf++)
#pragma unroll
            for (int j = 0; j < 2; j++) {
                acc[0][j][mf] = __builtin_amdgcn_mfma_f32_16x16x32_f16(xa[mf], wf0[j], acc[0][j][mf], 0, 0, 0);
                acc[1][j][mf] = __builtin_amdgcn_mfma_f32_16x16x32_f16(xa[mf], wf1[j], acc[1][j][mf], 0, 0, 0);
            }
    }
    // GLU epilogue -> swizzled LDS tile
#pragma unroll
    for (int j = 0; j < 2; j++) {
        int col = w * 32 + j * 16 + (lane & 15);
        float bbl = bl[col], bbg = bg[col];
#pragma unroll
        for (int mf = 0; mf < 4; mf++) {
            int rloc = mf * 16 + ((lane >> 4) << 2);
#pragma unroll
            for (int q = 0; q < 4; q++) {
                float lin = acc[0][j][mf][q] + bbl;
                float gat = acc[1][j][mf][q] + bbg;
                int row = rloc + q;
                ht[(row * 128 + col) ^ ((row & 7) << 3)] = (f16)(lin / (1.0f + expf(-gat)));
            }
        }
    }
    __syncthreads();
    // conv1 dual GEMM from ht
#pragma unroll
    for (int o = 0; o < 2; o++)
#pragma unroll
        for (int j = 0; j < 2; j++)
#pragma unroll
            for (int mf = 0; mf < 4; mf++) acc[o][j][mf] = (f32x4){0.f, 0.f, 0.f, 0.f};
    int row16 = lane & 15, kslot = lane >> 4;
    int swz = (row16 & 7) << 3;
#pragma unroll 1
    for (int kt = 0; kt < 4; kt++) {
        f16x8 wf0[2], wf1[2], xa[4];
#pragma unroll
        for (int j = 0; j < 2; j++) {
            wf0[j] = wfrag[((0 * 4 + kt) * 8 + (w * 2 + j)) * 64 + lane];
            wf1[j] = wfrag[((1 * 4 + kt) * 8 + (w * 2 + j)) * 64 + lane];
        }
#pragma unroll
        for (int mf = 0; mf < 4; mf++)
            xa[mf] = *(const f16x8*)&ht[((mf * 16 + row16) * 128 + kt * 32 + kslot * 8) ^ swz];
#pragma unroll
        for (int mf = 0; mf < 4; mf++)
#pragma unroll
            for (int j = 0; j < 2; j++) {
                acc[0][j][mf] = __builtin_amdgcn_mfma_f32_16x16x32_f16(xa[mf], wf0[j], acc[0][j][mf], 0, 0, 0);
                acc[1][j][mf] = __builtin_amdgcn_mfma_f32_16x16x32_f16(xa[mf], wf1[j], acc[1][j][mf], 0, 0, 0);
            }
    }
#pragma unroll
    for (int j = 0; j < 2; j++) {
        int col = w * 32 + j * 16 + (lane & 15);
        float bias = cb[col];
#pragma unroll
        for (int mf = 0; mf < 4; mf++) {
            int rbase = r0 + mf * 16 + ((lane >> 4) << 2);
#pragma unroll
            for (int q = 0; q < 4; q++) {
                A[(size_t)(rbase + q) * 128 + col] = (f16)(acc[0][j][mf][q] + bias);
                B[(size_t)(rbase + q) * 128 + col] = (f16)acc[1][j][mf][q];
            }
        }
    }
}

// ---------------------------------------------------------------- conv2 fused
// x1 = relu(A1 + window-max B1) (LDS only); pool x1 partials; A2/B2 = x1@W'.
// Gather loop: 8 ch/thread, ds_read_b128 + packed f16 max (exact).
__global__ __launch_bounds__(256) void k_conv2f(
    const f16* __restrict__ A1, const f16* __restrict__ B1,
    const signed char* __restrict__ nbroff, const f16x8* __restrict__ wfrag,
    const float* __restrict__ cb, f16* __restrict__ A2, f16* __restrict__ B2,
    float* __restrict__ partM1, float* __restrict__ partS1) {
    __shared__ f16 Bwin[96 * 128];            // rank window [r0-16, r0+80)
    __shared__ f16 x1t[64 * 128];             // XOR-swizzled GEMM input tile
    __shared__ float redM[4 * 128];
    __shared__ float redS[4 * 128];
    int tid = threadIdx.x;
    int bx = blockIdx.x;
    int r0 = bx * 64;
    int r0loc = (bx & 15) * 64;
#pragma unroll
    for (int p = 0; p < 6; p++) {
        int idx = tid + p * 256;              // [0,1536)
        int row = idx >> 4, kq = idx & 15;
        int gl = r0loc - 16 + row;
        f16x8 v;
#pragma unroll
        for (int i = 0; i < 8; i++) v[i] = (f16)0.0f;
        if (gl >= 0 && gl < NPG)
            v = *(const f16x8*)(B1 + (size_t)(r0 - 16 + row) * 128 + kq * 8);
        *(f16x8*)&Bwin[row * 128 + kq * 8] = v;
    }
    __syncthreads();
    int w = tid >> 6, lane = tid & 63;
    int rquad = lane >> 4;                    // row within 4-row group
    int c0 = (lane & 15) * 8;                 // channel octet
    float pm[8], ps[8];
#pragma unroll
    for (int i = 0; i < 8; i++) { pm[i] = -BINF; ps[i] = 0.f; }
#pragma unroll 1
    for (int rr = 0; rr < 4; rr++) {
        int row = w * 16 + rr * 4 + rquad;
        int grow = r0 + row;
        int4 ov = *(const int4*)(nbroff + (size_t)grow * 16);
        const int* ow = (const int*)&ov;
        f16x8 m;
#pragma unroll
        for (int i = 0; i < 8; i++) m[i] = (f16)(-INFINITY);
        const char* bbase = (const char*)Bwin + (size_t)(row + 16) * 256 + c0 * 2;
#pragma unroll
        for (int q = 0; q < 16; q++) {
            int off = (int)(signed char)((ow[q >> 2] >> ((q & 3) * 8)) & 0xff);
            f16x8 bv = *(const f16x8*)(bbase + off * 256);
            m = __builtin_elementwise_max(m, bv);
        }
        f16x8 av = *(const f16x8*)(A1 + (size_t)grow * 128 + c0);
        f16x8 ou;
#pragma unroll
        for (int i = 0; i < 8; i++) {
            float v = fmaxf((float)av[i] + (float)m[i], 0.0f);
            pm[i] = fmaxf(pm[i], v);
            ps[i] += v;
            ou[i] = (f16)v;
        }
        int idx = (row * 128 + c0) ^ ((row & 7) << 3);
        *(f16x8*)&x1t[idx] = ou;
    }
    // pool reduce: across rquad groups via shuffles, then across waves via LDS
#pragma unroll
    for (int i = 0; i < 8; i++) {
        pm[i] = fmaxf(pm[i], __shfl_xor(pm[i], 16));
        pm[i] = fmaxf(pm[i], __shfl_xor(pm[i], 32));
        ps[i] += __shfl_xor(ps[i], 16);
        ps[i] += __shfl_xor(ps[i], 32);
    }
    if (rquad == 0) {
#pragma unroll
        for (int i = 0; i < 8; i++) {
            redM[w * 128 + c0 + i] = pm[i];
            redS[w * 128 + c0 + i] = ps[i];
        }
    }
    __syncthreads();
    if (tid < 128) {
        float M = -BINF, S = 0.f;
#pragma unroll
        for (int w2 = 0; w2 < 4; w2++) {
            M = fmaxf(M, redM[w2 * 128 + tid]);
            S += redS[w2 * 128 + tid];
        }
        partM1[(size_t)bx * 128 + tid] = M;
        partS1[(size_t)bx * 128 + tid] = S;
    }
    f32x4 acc[2][2][4];
#pragma unroll
    for (int o = 0; o < 2; o++)
#pragma unroll
        for (int j = 0; j < 2; j++)
#pragma unroll
            for (int mf = 0; mf < 4; mf++) acc[o][j][mf] = (f32x4){0.f, 0.f, 0.f, 0.f};
    int row16 = lane & 15, kslot = lane >> 4;
    int swz = (row16 & 7) << 3;
#pragma unroll 1
    for (int kt = 0; kt < 4; kt++) {
        f16x8 wf0[2], wf1[2], xa[4];
#pragma unroll
        for (int j = 0; j < 2; j++) {
            wf0[j] = wfrag[((0 * 4 + kt) * 8 + (w * 2 + j)) * 64 + lane];
            wf1[j] = wfrag[((1 * 4 + kt) * 8 + (w * 2 + j)) * 64 + lane];
        }
#pragma unroll
        for (int mf = 0; mf < 4; mf++)
            xa[mf] = *(const f16x8*)&x1t[((mf * 16 + row16) * 128 + kt * 32 + kslot * 8) ^ swz];
#pragma unroll
        for (int mf = 0; mf < 4; mf++)
#pragma unroll
            for (int j = 0; j < 2; j++) {
                acc[0][j][mf] = __builtin_amdgcn_mfma_f32_16x16x32_f16(xa[mf], wf0[j], acc[0][j][mf], 0, 0, 0);
                acc[1][j][mf] = __builtin_amdgcn_mfma_f32_16x16x32_f16(xa[mf], wf1[j], acc[1][j][mf], 0, 0, 0);
            }
    }
#pragma unroll
    for (int j = 0; j < 2; j++) {
        int col = w * 32 + j * 16 + (lane & 15);
        float bias = cb[col];
#pragma unroll
        for (int mf = 0; mf < 4; mf++) {
            int rbase = r0 + mf * 16 + ((lane >> 4) << 2);
#pragma unroll
            for (int q = 0; q < 4; q++) {
                A2[(size_t)(rbase + q) * 128 + col] = (f16)(acc[0][j][mf][q] + bias);
                B2[(size_t)(rbase + q) * 128 + col] = (f16)acc[1][j][mf][q];
            }
        }
    }
}

// ---------------------------------------------------------------- gather2 + pool
// x2 computed in f32 registers from A2 + window-max B2; pooled, never stored.
__global__ __launch_bounds__(256) void k_gather2p(
    const f16* __restrict__ A2, const f16* __restrict__ B2,
    const signed char* __restrict__ nbroff,
    float* __restrict__ partM2, float* __restrict__ partS2) {
    __shared__ f16 Bwin[96 * 128];
    __shared__ float redM[4 * 128];
    __shared__ float redS[4 * 128];
    int tid = threadIdx.x;
    int bx = blockIdx.x;
    int r0 = bx * 64;
    int r0loc = (bx & 15) * 64;
#pragma unroll
    for (int p = 0; p < 6; p++) {
        int idx = tid + p * 256;
        int row = idx >> 4, kq = idx & 15;
        int gl = r0loc - 16 + row;
        f16x8 v;
#pragma unroll
        for (int i = 0; i < 8; i++) v[i] = (f16)0.0f;
        if (gl >= 0 && gl < NPG)
            v = *(const f16x8*)(B2 + (size_t)(r0 - 16 + row) * 128 + kq * 8);
        *(f16x8*)&Bwin[row * 128 + kq * 8] = v;
    }
    __syncthreads();
    int w = tid >> 6, lane = tid & 63;
    int rquad = lane >> 4;
    int c0 = (lane & 15) * 8;
    float pm[8], ps[8];
#pragma unroll
    for (int i = 0; i < 8; i++) { pm[i] = -BINF; ps[i] = 0.f; }
#pragma unroll 1
    for (int rr = 0; rr < 4; rr++) {
        int row = w * 16 + rr * 4 + rquad;
        int grow = r0 + row;
        int4 ov = *(const int4*)(nbroff + (size_t)grow * 16);
        const int* ow = (const int*)&ov;
        f16x8 m;
#pragma unroll
        for (int i = 0; i < 8; i++) m[i] = (f16)(-INFINITY);
        const char* bbase = (const char*)Bwin + (size_t)(row + 16) * 256 + c0 * 2;
#pragma unroll
        for (int q = 0; q < 16; q++) {
            int off = (int)(signed char)((ow[q >> 2] >> ((q & 3) * 8)) & 0xff);
            f16x8 bv = *(const f16x8*)(bbase + off * 256);
            m = __builtin_elementwise_max(m, bv);
        }
        f16x8 av = *(const f16x8*)(A2 + (size_t)grow * 128 + c0);
#pragma unroll
        for (int i = 0; i < 8; i++) {
            float v = fmaxf((float)av[i] + (float)m[i], 0.0f);
            pm[i] = fmaxf(pm[i], v);
            ps[i] += v;
        }
    }
#pragma unroll
    for (int i = 0; i < 8; i++) {
        pm[i] = fmaxf(pm[i], __shfl_xor(pm[i], 16));
        pm[i] = fmaxf(pm[i], __shfl_xor(pm[i], 32));
        ps[i] += __shfl_xor(ps[i], 16);
        ps[i] += __shfl_xor(ps[i], 32);
    }
    if (rquad == 0) {
#pragma unroll
        for (int i = 0; i < 8; i++) {
            redM[w * 128 + c0 + i] = pm[i];
            redS[w * 128 + c0 + i] = ps[i];
        }
    }
    __syncthreads();
    if (tid < 128) {
        float M = -BINF, S = 0.f;
#pragma unroll
        for (int w2 = 0; w2 < 4; w2++) {
            M = fmaxf(M, redM[w2 * 128 + tid]);
            S += redS[w2 * 128 + tid];
        }
        partM2[(size_t)bx * 128 + tid] = M;
        partS2[(size_t)bx * 128 + tid] = S;
    }
}

// ---------------------------------------------------------------- final head
__global__ __launch_bounds__(256) void k_final(const float* __restrict__ partM1,
                                               const float* __restrict__ partS1,
                                               const float* __restrict__ partM2,
                                               const float* __restrict__ partS2,
                                               const float* __restrict__ fg_lw,
                                               const float* __restrict__ fg_lb,
                                               const float* __restrict__ fg_gw,
                                               const float* __restrict__ fg_gb,
                                               const float* __restrict__ out_w,
                                               const float* __restrict__ out_b,
                                               float* __restrict__ out) {
    __shared__ float pooled[512];
    __shared__ float linv[128], gatev[128];
    __shared__ float gluv[128];
    __shared__ float lg[2];
    int g = blockIdx.x, tid = threadIdx.x;

    const float* pM = (tid < 128) ? partM1 : partM2;
    const float* pS = (tid < 128) ? partS1 : partS2;
    int cc = tid & 127;
    float mx = -BINF, sm = 0.0f;
    for (int ch = 0; ch < 16; ch++) {
        mx = fmaxf(mx, pM[(size_t)(g * 16 + ch) * 128 + cc]);
        sm += pS[(size_t)(g * 16 + ch) * 128 + cc];
    }
    pooled[tid] = mx;
    pooled[256 + tid] = sm * (1.0f / 1024.0f);
    __syncthreads();

    float acc = 0.0f;
    if (tid < 128) {
        for (int k = 0; k < 512; k++) acc = fmaf(pooled[k], fg_lw[k * 128 + tid], acc);
        linv[tid] = acc + fg_lb[tid];
    } else {
        int c = tid - 128;
        for (int k = 0; k < 512; k++) acc = fmaf(pooled[k], fg_gw[k * 128 + c], acc);
        gatev[c] = acc + fg_gb[c];
    }
    __syncthreads();
    if (tid < 128) gluv[tid] = linv[tid] / (1.0f + expf(-gatev[tid]));
    __syncthreads();
    if (tid < 2) {
        float s = out_b[tid];
        for (int c = 0; c < 128; c++) s = fmaf(gluv[c], out_w[c * 2 + tid], s);
        lg[tid] = s;
    }
    __syncthreads();
    if (tid < 2) {
        float m = fmaxf(lg[0], lg[1]);
        float lse = m + logf(expf(lg[0] - m) + expf(lg[1] - m));
        out[g * 2 + tid] = lg[tid] - lse;
    }
}

// ---------------------------------------------------------------- launch
extern "C" void kernel_launch(void* const* d_in, const int* in_sizes, int n_in,
                              void* d_out, int out_size, void* d_ws, size_t ws_size,
                              hipStream_t stream) {
    const float* x     = (const float*)d_in[0];
    const float* te_w  = (const float*)d_in[1];
    const float* te_b  = (const float*)d_in[2];
    const float* ig_lw = (const float*)d_in[3];
    const float* ig_lb = (const float*)d_in[4];
    const float* ig_gw = (const float*)d_in[5];
    const float* ig_gb = (const float*)d_in[6];
    const float* c1_w  = (const float*)d_in[7];
    const float* c1_b  = (const float*)d_in[8];
    const float* c2_w  = (const float*)d_in[9];
    const float* c2_b  = (const float*)d_in[10];
    const float* fg_lw = (const float*)d_in[11];
    const float* fg_lb = (const float*)d_in[12];
    const float* fg_gw = (const float*)d_in[13];
    const float* fg_gb = (const float*)d_in[14];
    const float* out_w = (const float*)d_in[15];
    const float* out_b = (const float*)d_in[16];
    float* out = (float*)d_out;

    // workspace layout (~67 MB)
    char* p = (char*)d_ws;
    const size_t T16 = (size_t)NN * HID * sizeof(f16);   // 16 MB
    f16* A1 = (f16*)p; p += T16;
    f16* B1 = (f16*)p; p += T16;
    f16* A2 = (f16*)p; p += T16;
    f16* B2 = (f16*)p; p += T16;
    int* sidxg = (int*)p;            p += (size_t)NN * 4;
    signed char* nbroff = (signed char*)p; p += (size_t)NN * KNN;
    float* partM1 = (float*)p;       p += (size_t)1024 * 128 * 4;
    float* partS1 = (float*)p;       p += (size_t)1024 * 128 * 4;
    float* partM2 = (float*)p;       p += (size_t)1024 * 128 * 4;
    float* partS2 = (float*)p;       p += (size_t)1024 * 128 * 4;
    f16* gfrag = (f16*)p;            p += 16384 * 2;
    f16* f1 = (f16*)p;               p += 32768 * 2;
    f16* f2 = (f16*)p;               p += 32768 * 2;

    k_topk<<<NG + 80, 1024, 0, stream>>>(x, sidxg, nbroff, ig_lw, ig_gw,
                                         c1_w, c2_w, gfrag, f1, f2);
    k_fuse1<<<NN / 64, 256, 0, stream>>>(x, te_w, te_b, (const f16x8*)gfrag,
                                         ig_lb, ig_gb, sidxg, (const f16x8*)f1,
                                         c1_b, A1, B1);
    k_conv2f<<<NN / 64, 256, 0, stream>>>(A1, B1, nbroff, (const f16x8*)f2,
                                          c2_b, A2, B2, partM1, partS1);
    k_gather2p<<<NN / 64, 256, 0, stream>>>(A2, B2, nbroff, partM2, partS2);
    k_final<<<NG, 256, 0, stream>>>(partM1, partS1, partM2, partS2,
                                    fg_lw, fg_lb, fg_gw, fg_gb, out_w, out_b, out);
}